// Round 10
// baseline (958.200 us; speedup 1.0000x reference)
//
#include <hip/hip_runtime.h>
#include <hip/hip_bf16.h>
#include <math.h>

// B=2, C=64, 128x128 low-res, SCALE=4 -> 512x512, KUP=5, E=64
// d_out = [final | sapa | enc] each (2,64,512,512) f32

#define DEVFN static __device__ __forceinline__

typedef unsigned int u32x4 __attribute__((ext_vector_type(4)));

DEVFN float keys_w(float d) {
    if (d < 1.f) return ((1.5f * d - 2.5f) * d) * d + 1.f;
    if (d < 2.f) return ((-0.5f * d + 2.5f) * d - 4.f) * d + 2.f;
    return 0.f;
}

DEVFN void bicubic_axis(int o, int n, int idx4[4], float w4[4]) {
    // jax.image.resize 'cubic': sample=(o+0.5)/4-0.5, OOB taps dropped+renormalized
    float f = (o + 0.5f) * 0.25f - 0.5f;
    float fb = floorf(f);
    int ib = (int)fb;
    float t = f - fb;
    float ws[4];
    ws[0] = keys_w(1.f + t);
    ws[1] = keys_w(t);
    ws[2] = keys_w(1.f - t);
    ws[3] = keys_w(2.f - t);
    float s = 0.f;
#pragma unroll
    for (int m = 0; m < 4; m++) {
        int ix = ib - 1 + m;
        if (ix < 0 || ix >= n) ws[m] = 0.f;
        s += ws[m];
        idx4[m] = min(max(ix, 0), n - 1);
    }
    float inv = 1.f / s;
#pragma unroll
    for (int m = 0; m < 4; m++) w4[m] = ws[m] * inv;
}

DEVFN float sigm(float v) { return 1.f / (1.f + __expf(-v)); }

DEVFN unsigned short f2bf(float f) {
    __hip_bfloat16 h = __float2bfloat16(f);
    unsigned short u;
    __builtin_memcpy(&u, &h, 2);
    return u;
}
DEVFN float bf2f(unsigned short u) {
    union { unsigned int i; float f; } z;
    z.i = ((unsigned int)u) << 16;
    return z.f;
}
DEVFN float4 cvt4(uint2 u) {
    return make_float4(bf2f((unsigned short)(u.x & 0xffff)), bf2f((unsigned short)(u.x >> 16)),
                       bf2f((unsigned short)(u.y & 0xffff)), bf2f((unsigned short)(u.y >> 16)));
}

// ---------------- weight pre-transpose: w[oc][ic][tap] -> wT[tap][ic][oc] ----------------
__global__ __launch_bounds__(256) void k_prep(const float* __restrict__ w5,
                                              const float* __restrict__ w3a,
                                              const float* __restrict__ w3b,
                                              float* __restrict__ wT5,
                                              float* __restrict__ wT3a,
                                              float* __restrict__ wT3b) {
    int t = blockIdx.x * 256 + threadIdx.x;
    if (t < 6400) {
        int tap = t >> 8, ic = (t >> 4) & 15, oc = t & 15;
        wT5[t] = w5[(oc * 16 + ic) * 25 + tap];
    }
    if (t < 2304) {
        int tap = t >> 8, ic = (t >> 4) & 15, oc = t & 15;
        wT3a[t] = w3a[(oc * 16 + ic) * 9 + tap];
        wT3b[t] = w3b[(oc * 16 + ic) * 9 + tap];
    }
}

// ---------------- low-res fused: xbuf copy, k-proj, gate/pc1a projections ----------------
__global__ __launch_bounds__(256) void k_low(const float* __restrict__ x,
                                             const float* __restrict__ gw, const float* __restrict__ gb,
                                             const float* __restrict__ pw,
                                             const float* __restrict__ lg, const float* __restrict__ lb,
                                             const float* __restrict__ kw, const float* __restrict__ kbias,
                                             float* __restrict__ kb, float* __restrict__ xb,
                                             float* __restrict__ glo, float* __restrict__ plo) {
    int idx = blockIdx.x * 256 + threadIdx.x;  // 32768 px
    int w = idx & 127, h = (idx >> 7) & 127, b = idx >> 14;
    const float* xp = x + (size_t)b * 64 * 16384 + (h << 7) + w;
    float xv[64];
#pragma unroll
    for (int c = 0; c < 64; c++) xv[c] = xp[(size_t)c << 14];
    float4* xbp = (float4*)(xb + (size_t)idx * 64);
#pragma unroll
    for (int c4 = 0; c4 < 16; c4++)
        xbp[c4] = make_float4(xv[4 * c4], xv[4 * c4 + 1], xv[4 * c4 + 2], xv[4 * c4 + 3]);
    // gate projection on raw x (commutes with bicubic upsample)
    float4* gp = (float4*)(glo + (size_t)idx * 64);
#pragma unroll
    for (int e4 = 0; e4 < 16; e4++) {
        float r[4];
#pragma unroll
        for (int u = 0; u < 4; u++) {
            int e = e4 * 4 + u;
            float s = gb[e];
#pragma unroll
            for (int c = 0; c < 64; c++) s = fmaf(xv[c], gw[e * 64 + c], s);
            r[u] = s;
        }
        gp[e4] = make_float4(r[0], r[1], r[2], r[3]);
    }
    // pc1a x-part projection (bias + y-part added at hi-res)
    float4* pp = (float4*)(plo + (size_t)idx * 16);
#pragma unroll
    for (int e4 = 0; e4 < 4; e4++) {
        float r[4];
#pragma unroll
        for (int u = 0; u < 4; u++) {
            int e = e4 * 4 + u;
            float s = 0.f;
#pragma unroll
            for (int c = 0; c < 64; c++) s = fmaf(xv[c], pw[e * 67 + 3 + c], s);
            r[u] = s;
        }
        pp[e4] = make_float4(r[0], r[1], r[2], r[3]);
    }
    // layernorm + k projection
    float m = 0.f;
#pragma unroll
    for (int c = 0; c < 64; c++) m += xv[c];
    m *= (1.f / 64.f);
    float var = 0.f;
#pragma unroll
    for (int c = 0; c < 64; c++) {
        float d = xv[c] - m;
        var = fmaf(d, d, var);
    }
    var *= (1.f / 64.f);
    float rstd = rsqrtf(var + 1e-5f);
#pragma unroll
    for (int c = 0; c < 64; c++) xv[c] = (xv[c] - m) * rstd * lg[c] + lb[c];
    float4* kp = (float4*)(kb + (size_t)idx * 64);
#pragma unroll
    for (int e4 = 0; e4 < 16; e4++) {
        float r[4];
#pragma unroll
        for (int u = 0; u < 4; u++) {
            int e = e4 * 4 + u;
            float s = kbias[e];
#pragma unroll
            for (int c = 0; c < 64; c++) s = fmaf(xv[c], kw[e * 64 + c], s);
            r[u] = s;
        }
        kp[e4] = make_float4(r[0], r[1], r[2], r[3]);
    }
}

// ---------------- separable bicubic upsample -> gate bf16 chlast + f0 bf16 chlast ----------------
__global__ __launch_bounds__(256) void k_gp(const float* __restrict__ glo, const float* __restrict__ plo,
                                            const float* __restrict__ y,
                                            const float* __restrict__ paw, const float* __restrict__ pab,
                                            unsigned short* __restrict__ gate, unsigned short* __restrict__ f0) {
    __shared__ float v[68 * 81];  // [col][ch], stride 81 to spread banks
    int bid = blockIdx.x;
    int b = bid >> 10, i = (bid >> 1) & 511, j0 = (bid & 1) << 8;
    int t = threadIdx.x;
    int iy[4];
    float wy[4];
    bicubic_axis(i, 128, iy, wy);
    int c0 = (j0 >> 2) - 2;
    // vertical pass into LDS
    for (int e = t; e < 68 * 80; e += 256) {
        int ch = e % 80, lc = e / 80;
        int gc = c0 + lc;
        float val = 0.f;
        if ((unsigned)gc < 128u) {
            if (ch < 64) {
                val = wy[0] * glo[(size_t)((b * 128 + iy[0]) * 128 + gc) * 64 + ch] +
                      wy[1] * glo[(size_t)((b * 128 + iy[1]) * 128 + gc) * 64 + ch] +
                      wy[2] * glo[(size_t)((b * 128 + iy[2]) * 128 + gc) * 64 + ch] +
                      wy[3] * glo[(size_t)((b * 128 + iy[3]) * 128 + gc) * 64 + ch];
            } else {
                int cc = ch - 64;
                val = wy[0] * plo[(size_t)((b * 128 + iy[0]) * 128 + gc) * 16 + cc] +
                      wy[1] * plo[(size_t)((b * 128 + iy[1]) * 128 + gc) * 16 + cc] +
                      wy[2] * plo[(size_t)((b * 128 + iy[2]) * 128 + gc) * 16 + cc] +
                      wy[3] * plo[(size_t)((b * 128 + iy[3]) * 128 + gc) * 16 + cc];
            }
        }
        v[lc * 81 + ch] = val;
    }
    __syncthreads();
    // horizontal pass: one px per thread
    int j = j0 + t;
    int jx[4];
    float wx[4];
    bicubic_axis(j, 128, jx, wx);
    int lx0 = jx[0] - c0, lx1 = jx[1] - c0, lx2 = jx[2] - c0, lx3 = jx[3] - c0;
    float out[80];
#pragma unroll
    for (int ch = 0; ch < 80; ch++)
        out[ch] = wx[0] * v[lx0 * 81 + ch] + wx[1] * v[lx1 * 81 + ch] +
                  wx[2] * v[lx2 * 81 + ch] + wx[3] * v[lx3 * 81 + ch];
    size_t pxoff = ((size_t)b << 18) + ((size_t)i << 9) + j;
    // gate: sigmoid -> bf16 packed nontemporal stores (64 ch)
    u32x4* gp4 = (u32x4*)(gate + pxoff * 64);
#pragma unroll
    for (int k4 = 0; k4 < 8; k4++) {
        u32x4 pk;
#pragma unroll
        for (int u = 0; u < 4; u++) {
            int k = k4 * 4 + u;
            pk[u] = (unsigned int)f2bf(sigm(out[2 * k])) | ((unsigned int)f2bf(sigm(out[2 * k + 1])) << 16);
        }
        __builtin_nontemporal_store(pk, gp4 + k4);
    }
    // f0 = up(p_lo) + W_y*y + b  -> bf16 chlast (consumed by conv5 soon: keep cached)
    float yc0 = y[((size_t)(b * 3 + 0) << 18) + ((size_t)i << 9) + j];
    float yc1 = y[((size_t)(b * 3 + 1) << 18) + ((size_t)i << 9) + j];
    float yc2 = y[((size_t)(b * 3 + 2) << 18) + ((size_t)i << 9) + j];
    float r[16];
#pragma unroll
    for (int oc = 0; oc < 16; oc++)
        r[oc] = out[64 + oc] + pab[oc] + yc0 * paw[oc * 67 + 0] + yc1 * paw[oc * 67 + 1] + yc2 * paw[oc * 67 + 2];
    uint4* fp = (uint4*)(f0 + pxoff * 16);
#pragma unroll
    for (int h4 = 0; h4 < 2; h4++) {
        unsigned int pk[4];
#pragma unroll
        for (int u = 0; u < 4; u++) {
            int k = h4 * 4 + u;
            pk[u] = (unsigned int)f2bf(r[2 * k]) | ((unsigned int)f2bf(r[2 * k + 1]) << 16);
        }
        fp[h4] = make_uint4(pk[0], pk[1], pk[2], pk[3]);
    }
}

// ---------------- 5x5 conv 16->16 pad2, LDS-staged (bf16 global, f32 LDS) ----------------
__global__ __launch_bounds__(256) void k_conv5(const unsigned short* __restrict__ fin,
                                               const float* __restrict__ wT,
                                               const float* __restrict__ bias,
                                               unsigned short* __restrict__ fout) {
    __shared__ float lds[8 * 68 * 20];  // 43,520 B
    int tid = threadIdx.x;
    int bid = blockIdx.x;  // 2048 = 2 * 128 * 8
    int seg = bid & 7, it = (bid >> 3) & 127, b = bid >> 10;
    int i0 = it * 4, j0 = seg * 64;
    for (int s = tid; s < 2176; s += 256) {  // 8*68 px * 4 parts(4ch)
        int part = s & 3, px = s >> 2;
        int row = px / 68, col = px - row * 68;
        int gi = i0 - 2 + row, gj = j0 - 2 + col;
        float4 v = make_float4(0.f, 0.f, 0.f, 0.f);
        if ((unsigned)gi < 512u && (unsigned)gj < 512u) {
            uint2 u = *(const uint2*)(fin + (((size_t)b << 18) + ((size_t)gi << 9) + gj) * 16 + part * 4);
            v = cvt4(u);
        }
        *(float4*)(&lds[(row * 68 + col) * 20 + part * 4]) = v;
    }
    __syncthreads();
    int tx = tid & 63, ty = tid >> 6;
    float acc[16];
#pragma unroll
    for (int oc = 0; oc < 16; oc++) acc[oc] = bias[oc];
#pragma unroll
    for (int ky = 0; ky < 5; ky++) {
#pragma unroll
        for (int kx = 0; kx < 5; kx++) {
            const float* p = &lds[((ty + ky) * 68 + tx + kx) * 20];
            float vv[16];
            *(float4*)(vv + 0) = *(const float4*)(p + 0);
            *(float4*)(vv + 4) = *(const float4*)(p + 4);
            *(float4*)(vv + 8) = *(const float4*)(p + 8);
            *(float4*)(vv + 12) = *(const float4*)(p + 12);
            const float* wp = wT + (ky * 5 + kx) * 256;
#pragma unroll
            for (int ic = 0; ic < 16; ic++) {
                float v = vv[ic];
#pragma unroll
                for (int oc = 0; oc < 16; oc++)
                    acc[oc] = fmaf(v, wp[ic * 16 + oc], acc[oc]);
            }
        }
    }
    int i = i0 + ty, j = j0 + tx;
    uint4* op = (uint4*)(fout + (((size_t)b << 18) + ((size_t)i << 9) + j) * 16);
#pragma unroll
    for (int h4 = 0; h4 < 2; h4++) {
        unsigned int pk[4];
#pragma unroll
        for (int u = 0; u < 4; u++) {
            int k = h4 * 4 + u;
            pk[u] = (unsigned int)f2bf(acc[2 * k]) | ((unsigned int)f2bf(acc[2 * k + 1]) << 16);
        }
        op[h4] = make_uint4(pk[0], pk[1], pk[2], pk[3]);
    }
}

// ---------------- 3x3 conv 16->16 pad1 + relu, LDS-staged (bf16 global) ----------------
__global__ __launch_bounds__(256) void k_conv3r(const unsigned short* __restrict__ fin,
                                                const float* __restrict__ wT,
                                                const float* __restrict__ bias,
                                                unsigned short* __restrict__ fout) {
    __shared__ float lds[6 * 66 * 20];  // 31,680 B
    int tid = threadIdx.x;
    int bid = blockIdx.x;
    int seg = bid & 7, it = (bid >> 3) & 127, b = bid >> 10;
    int i0 = it * 4, j0 = seg * 64;
    for (int s = tid; s < 1584; s += 256) {  // 6*66 px * 4 parts
        int part = s & 3, px = s >> 2;
        int row = px / 66, col = px - row * 66;
        int gi = i0 - 1 + row, gj = j0 - 1 + col;
        float4 v = make_float4(0.f, 0.f, 0.f, 0.f);
        if ((unsigned)gi < 512u && (unsigned)gj < 512u) {
            uint2 u = *(const uint2*)(fin + (((size_t)b << 18) + ((size_t)gi << 9) + gj) * 16 + part * 4);
            v = cvt4(u);
        }
        *(float4*)(&lds[(row * 66 + col) * 20 + part * 4]) = v;
    }
    __syncthreads();
    int tx = tid & 63, ty = tid >> 6;
    float acc[16];
#pragma unroll
    for (int oc = 0; oc < 16; oc++) acc[oc] = bias[oc];
#pragma unroll
    for (int ky = 0; ky < 3; ky++) {
#pragma unroll
        for (int kx = 0; kx < 3; kx++) {
            const float* p = &lds[((ty + ky) * 66 + tx + kx) * 20];
            float vv[16];
            *(float4*)(vv + 0) = *(const float4*)(p + 0);
            *(float4*)(vv + 4) = *(const float4*)(p + 4);
            *(float4*)(vv + 8) = *(const float4*)(p + 8);
            *(float4*)(vv + 12) = *(const float4*)(p + 12);
            const float* wp = wT + (ky * 3 + kx) * 256;
#pragma unroll
            for (int ic = 0; ic < 16; ic++) {
                float v = vv[ic];
#pragma unroll
                for (int oc = 0; oc < 16; oc++)
                    acc[oc] = fmaf(v, wp[ic * 16 + oc], acc[oc]);
            }
        }
    }
    int i = i0 + ty, j = j0 + tx;
    uint4* op = (uint4*)(fout + (((size_t)b << 18) + ((size_t)i << 9) + j) * 16);
#pragma unroll
    for (int h4 = 0; h4 < 2; h4++) {
        unsigned int pk[4];
#pragma unroll
        for (int u = 0; u < 4; u++) {
            int k = h4 * 4 + u;
            pk[u] = (unsigned int)f2bf(fmaxf(acc[2 * k], 0.f)) |
                    ((unsigned int)f2bf(fmaxf(acc[2 * k + 1], 0.f)) << 16);
        }
        op[h4] = make_uint4(pk[0], pk[1], pk[2], pk[3]);
    }
}

// ---------------- spa2(t)+f1 residual, frq chain, cat -> f8 f32 (bf16 inputs) ----------------
__global__ __launch_bounds__(256) void k_tail(const unsigned short* __restrict__ f1,
                                              const unsigned short* __restrict__ t,
                                              const float* __restrict__ wT2,
                                              const float* __restrict__ s2b,
                                              const float* __restrict__ q1w, const float* __restrict__ q1b,
                                              const float* __restrict__ q2w, const float* __restrict__ q2b,
                                              const float* __restrict__ cw_, const float* __restrict__ cb_,
                                              float* __restrict__ f8) {
    __shared__ float lds[6 * 66 * 20];
    int tid = threadIdx.x;
    int bid = blockIdx.x;
    int seg = bid & 7, it = (bid >> 3) & 127, b = bid >> 10;
    int i0 = it * 4, j0 = seg * 64;
    for (int s = tid; s < 1584; s += 256) {
        int part = s & 3, px = s >> 2;
        int row = px / 66, col = px - row * 66;
        int gi = i0 - 1 + row, gj = j0 - 1 + col;
        float4 v = make_float4(0.f, 0.f, 0.f, 0.f);
        if ((unsigned)gi < 512u && (unsigned)gj < 512u) {
            uint2 u = *(const uint2*)(t + (((size_t)b << 18) + ((size_t)gi << 9) + gj) * 16 + part * 4);
            v = cvt4(u);
        }
        *(float4*)(&lds[(row * 66 + col) * 20 + part * 4]) = v;
    }
    __syncthreads();
    int tx = tid & 63, ty = tid >> 6;
    int i = i0 + ty, j = j0 + tx;
    float sp[16];
#pragma unroll
    for (int oc = 0; oc < 16; oc++) sp[oc] = s2b[oc];
#pragma unroll
    for (int ky = 0; ky < 3; ky++) {
#pragma unroll
        for (int kx = 0; kx < 3; kx++) {
            const float* p = &lds[((ty + ky) * 66 + tx + kx) * 20];
            float vv[16];
            *(float4*)(vv + 0) = *(const float4*)(p + 0);
            *(float4*)(vv + 4) = *(const float4*)(p + 4);
            *(float4*)(vv + 8) = *(const float4*)(p + 8);
            *(float4*)(vv + 12) = *(const float4*)(p + 12);
            const float* wp = wT2 + (ky * 3 + kx) * 256;
#pragma unroll
            for (int ic = 0; ic < 16; ic++) {
                float v = vv[ic];
#pragma unroll
                for (int oc = 0; oc < 16; oc++)
                    sp[oc] = fmaf(v, wp[ic * 16 + oc], sp[oc]);
            }
        }
    }
    // own-pixel f1 (residual + frq input), bf16
    float fv[16];
    {
        const uint2* f1p = (const uint2*)(f1 + (((size_t)b << 18) + ((size_t)i << 9) + j) * 16);
#pragma unroll
        for (int h4 = 0; h4 < 4; h4++) {
            float4 v = cvt4(f1p[h4]);
            fv[4 * h4 + 0] = v.x; fv[4 * h4 + 1] = v.y; fv[4 * h4 + 2] = v.z; fv[4 * h4 + 3] = v.w;
        }
    }
#pragma unroll
    for (int c = 0; c < 16; c++) sp[c] += fv[c];
    float mid[16];
#pragma unroll
    for (int r = 0; r < 16; r++) {
        float m = q1b[r];
#pragma unroll
        for (int c = 0; c < 16; c++) m = fmaf(fv[c], q1w[r * 16 + c], m);
        mid[r] = fmaxf(m, 0.f);
    }
    float fo[16];
#pragma unroll
    for (int r = 0; r < 16; r++) {
        float m = q2b[r];
#pragma unroll
        for (int c = 0; c < 16; c++) m = fmaf(mid[c], q2w[r * 16 + c], m);
        fo[r] = m;
    }
    float r8[8];
#pragma unroll
    for (int o = 0; o < 8; o++) {
        float a = cb_[o];
#pragma unroll
        for (int c = 0; c < 16; c++) a = fmaf(sp[c], cw_[o * 32 + c], a);
#pragma unroll
        for (int c = 0; c < 16; c++) a = fmaf(fo[c], cw_[o * 32 + 16 + c], a);
        r8[o] = a;
    }
    float4* op = (float4*)(f8 + (((size_t)b << 18) + ((size_t)i << 9) + j) * 8);
    op[0] = make_float4(r8[0], r8[1], r8[2], r8[3]);
    op[1] = make_float4(r8[4], r8[5], r8[6], r8[7]);
}

// ---------------- pooled mean partials (channel-last f8) ----------------
__global__ __launch_bounds__(256) void k_pool(const float* __restrict__ f8, float* __restrict__ partials) {
    int b = blockIdx.x >> 4, blk = blockIdx.x & 15;
    const float4* fp = (const float4*)(f8 + (((size_t)b) << 18) * 8);
    float acc[8];
#pragma unroll
    for (int c = 0; c < 8; c++) acc[c] = 0.f;
    int p0 = blk * 16384;
    for (int p = p0 + threadIdx.x; p < p0 + 16384; p += 256) {
        float4 a0 = fp[p * 2], a1 = fp[p * 2 + 1];
        acc[0] += a0.x; acc[1] += a0.y; acc[2] += a0.z; acc[3] += a0.w;
        acc[4] += a1.x; acc[5] += a1.y; acc[6] += a1.z; acc[7] += a1.w;
    }
#pragma unroll
    for (int off = 32; off; off >>= 1) {
#pragma unroll
        for (int c = 0; c < 8; c++) acc[c] += __shfl_down(acc[c], off, 64);
    }
    __shared__ float ls[4][8];
    int lane = threadIdx.x & 63, wv = threadIdx.x >> 6;
    if (lane == 0) {
#pragma unroll
        for (int c = 0; c < 8; c++) ls[wv][c] = acc[c];
    }
    __syncthreads();
    if (threadIdx.x < 8) {
        float s = ls[0][threadIdx.x] + ls[1][threadIdx.x] + ls[2][threadIdx.x] + ls[3][threadIdx.x];
        partials[(b * 8 + threadIdx.x) * 16 + blk] = s;
    }
}

__global__ void k_se(const float* __restrict__ partials,
                     const float* __restrict__ w1, const float* __restrict__ b1,
                     const float* __restrict__ w2, const float* __restrict__ b2,
                     float* __restrict__ cw) {
    int b = threadIdx.x;
    if (b >= 2) return;
    float pooled[8];
#pragma unroll
    for (int c = 0; c < 8; c++) {
        float s = 0.f;
#pragma unroll
        for (int k = 0; k < 16; k++) s += partials[(b * 8 + c) * 16 + k];
        pooled[c] = s * (1.f / 262144.f);
    }
    float mid[2];
#pragma unroll
    for (int r = 0; r < 2; r++) {
        float m = b1[r];
#pragma unroll
        for (int c = 0; c < 8; c++) m = fmaf(w1[r * 8 + c], pooled[c], m);
        mid[r] = fmaxf(m, 0.f);
    }
#pragma unroll
    for (int c = 0; c < 8; c++) {
        float v = b2[c] + w2[c * 2 + 0] * mid[0] + w2[c * 2 + 1] * mid[1];
        cw[b * 8 + c] = 1.f / (1.f + __expf(-v));
    }
}

// ---------------- enc = conv1x1_8->64(f8*cw) + fused LN(lny) + q-proj -> qbuf bf16 chlast ----------------
__global__ __launch_bounds__(256) void k_pc3(const float* __restrict__ f8, const float* __restrict__ cw,
                                             const float* __restrict__ w, const float* __restrict__ bias,
                                             const float* __restrict__ lg, const float* __restrict__ lb,
                                             const float* __restrict__ qw, const float* __restrict__ qbias,
                                             float* __restrict__ enc, unsigned short* __restrict__ qbuf) {
    int idx = blockIdx.x * 256 + threadIdx.x;
    int b = idx >> 18;
    size_t hi = (size_t)idx & 262143;
    const float4* fp = (const float4*)(f8 + (size_t)idx * 8);
    float4 a0 = fp[0], a1 = fp[1];
    float v[8] = {a0.x, a0.y, a0.z, a0.w, a1.x, a1.y, a1.z, a1.w};
#pragma unroll
    for (int c = 0; c < 8; c++) v[c] *= cw[b * 8 + c];
    float yn[64];
#pragma unroll
    for (int oc = 0; oc < 64; oc++) {
        float a = bias[oc];
#pragma unroll
        for (int c = 0; c < 8; c++) a = fmaf(v[c], w[oc * 8 + c], a);
        yn[oc] = a;
        __builtin_nontemporal_store(a, &enc[((size_t)(b * 64 + oc) << 18) + hi]);
    }
    // layernorm (lny) over the 64 channels (all in regs)
    float m = 0.f;
#pragma unroll
    for (int c = 0; c < 64; c++) m += yn[c];
    m *= (1.f / 64.f);
    float var = 0.f;
#pragma unroll
    for (int c = 0; c < 64; c++) {
        float d = yn[c] - m;
        var = fmaf(d, d, var);
    }
    var *= (1.f / 64.f);
    float rstd = rsqrtf(var + 1e-5f);
#pragma unroll
    for (int c = 0; c < 64; c++) yn[c] = (yn[c] - m) * rstd * lg[c] + lb[c];
    // q projection, store bf16 channel-last (nontemporal: >L2, read next kernel)
    unsigned short* qp = qbuf + (size_t)idx * 64;
    for (int e0 = 0; e0 < 64; e0 += 8) {
        float qv[8];
#pragma unroll
        for (int u = 0; u < 8; u++) {
            float s = qbias[e0 + u];
#pragma unroll
            for (int c = 0; c < 64; c++) s = fmaf(yn[c], qw[(e0 + u) * 64 + c], s);
            qv[u] = s;
        }
        u32x4 pk;
#pragma unroll
        for (int u = 0; u < 4; u++)
            pk[u] = (unsigned int)f2bf(qv[2 * u]) | ((unsigned int)f2bf(qv[2 * u + 1]) << 16);
        __builtin_nontemporal_store(pk, (u32x4*)(qp + e0));
    }
}

// ---------------- attention + blend: row-tile (1 i x 64 j), 4 threads/pixel ----------------
// enc is RECOMPUTED from f8 (16MB) instead of re-read (134MB). qbuf/gate loads nontemporal.
__global__ __launch_bounds__(256, 4) void k_attn(const float* __restrict__ f8, const float* __restrict__ cwp,
                                                 const float* __restrict__ pw, const float* __restrict__ pb,
                                                 const unsigned short* __restrict__ gate,
                                                 const unsigned short* __restrict__ qb,
                                                 const float* __restrict__ kb, const float* __restrict__ xbv,
                                                 float* __restrict__ sapa, float* __restrict__ fin) {
    __shared__ float tile[100 * 68];  // 27,200 B
    int tid = threadIdx.x;
    int bid = blockIdx.x;  // 2 * 512 * 8
    int b = bid >> 12, i = (bid >> 3) & 511, jb = bid & 7;
    int j0 = jb << 6;
    int h = i >> 2;
    int wbase = j0 >> 2;
    int cg = tid & 3, px = tid >> 2;
    int j = j0 + px;
    size_t pix = ((size_t)b << 18) + ((size_t)i << 9) + j;
    // this thread's 16 q-components (e-group = cg), bf16 channel-last, nontemporal
    const u32x4* qp = (const u32x4*)(qb + pix * 64 + cg * 16);
    u32x4 q0 = __builtin_nontemporal_load(qp), q1 = __builtin_nontemporal_load(qp + 1);
    unsigned int qu[8] = {q0[0], q0[1], q0[2], q0[3], q1[0], q1[1], q1[2], q1[3]};
    float q[16];
#pragma unroll
    for (int k = 0; k < 8; k++) {
        q[2 * k] = bf2f((unsigned short)(qu[k] & 0xffff));
        q[2 * k + 1] = bf2f((unsigned short)(qu[k] >> 16));
    }
    // ---- phase 1: stage K halo (5x20), zero-filled OOB ----
    for (int s = tid; s < 1600; s += 256) {
        int p = s >> 4, e4 = s & 15;
        int row = p / 20, col = p - row * 20;
        int hh = h - 2 + row, ww = wbase - 2 + col;
        float4 val = make_float4(0.f, 0.f, 0.f, 0.f);
        if ((unsigned)hh < 128u && (unsigned)ww < 128u)
            val = ((const float4*)(kb + (size_t)((b * 128 + hh) * 128 + ww) * 64))[e4];
        *(float4*)(tile + p * 68 + e4 * 4) = val;
    }
    __syncthreads();
    int wl = px >> 2;
    float a[25];
#pragma unroll
    for (int dy = 0; dy < 5; dy++) {
#pragma unroll
        for (int dx = 0; dx < 5; dx++) {
            int lp = dy * 20 + wl + dx;
            const float4* kp = (const float4*)(tile + lp * 68 + cg * 16);
            float s = 0.f;
#pragma unroll
            for (int e4 = 0; e4 < 4; e4++) {
                float4 kv = kp[e4];
                s = fmaf(q[4 * e4 + 0], kv.x, s);
                s = fmaf(q[4 * e4 + 1], kv.y, s);
                s = fmaf(q[4 * e4 + 2], kv.z, s);
                s = fmaf(q[4 * e4 + 3], kv.w, s);
            }
            a[dy * 5 + dx] = s;
        }
    }
#pragma unroll
    for (int p = 0; p < 25; p++) {
        a[p] += __shfl_xor(a[p], 1, 4);
        a[p] += __shfl_xor(a[p], 2, 4);
    }
    float mx = a[0];
#pragma unroll
    for (int p = 1; p < 25; p++) mx = fmaxf(mx, a[p]);
    float Z = 0.f;
#pragma unroll
    for (int p = 0; p < 25; p++) {
        a[p] = __expf(a[p] - mx);
        Z += a[p];
    }
    float invZ = 1.f / Z;
    __syncthreads();
    // ---- phase 2: stage X halo ----
    for (int s = tid; s < 1600; s += 256) {
        int p = s >> 4, e4 = s & 15;
        int row = p / 20, col = p - row * 20;
        int hh = h - 2 + row, ww = wbase - 2 + col;
        float4 val = make_float4(0.f, 0.f, 0.f, 0.f);
        if ((unsigned)hh < 128u && (unsigned)ww < 128u)
            val = ((const float4*)(xbv + (size_t)((b * 128 + hh) * 128 + ww) * 64))[e4];
        *(float4*)(tile + p * 68 + e4 * 4) = val;
    }
    __syncthreads();
    float o[16];
#pragma unroll
    for (int k = 0; k < 16; k++) o[k] = 0.f;
#pragma unroll
    for (int dy = 0; dy < 5; dy++) {
#pragma unroll
        for (int dx = 0; dx < 5; dx++) {
            float wp = a[dy * 5 + dx];
            int lp = dy * 20 + wl + dx;
            const float4* xp = (const float4*)(tile + lp * 68 + cg * 16);
#pragma unroll
            for (int e4 = 0; e4 < 4; e4++) {
                float4 xv = xp[e4];
                o[4 * e4 + 0] = fmaf(wp, xv.x, o[4 * e4 + 0]);
                o[4 * e4 + 1] = fmaf(wp, xv.y, o[4 * e4 + 1]);
                o[4 * e4 + 2] = fmaf(wp, xv.z, o[4 * e4 + 2]);
                o[4 * e4 + 3] = fmaf(wp, xv.w, o[4 * e4 + 3]);
            }
        }
    }
    // ---- epilogue: recompute enc from f8 (own px), gate bf16, nontemporal writes ----
    const float4* fp8 = (const float4*)(f8 + pix * 8);
    float4 a08 = fp8[0], a18 = fp8[1];
    float v8[8] = {a08.x, a08.y, a08.z, a08.w, a18.x, a18.y, a18.z, a18.w};
#pragma unroll
    for (int c = 0; c < 8; c++) v8[c] *= cwp[b * 8 + c];
    const u32x4* gp4 = (const u32x4*)(gate + pix * 64 + cg * 16);
    u32x4 g0 = __builtin_nontemporal_load(gp4), g1 = __builtin_nontemporal_load(gp4 + 1);
    unsigned int gu[8] = {g0[0], g0[1], g0[2], g0[3], g1[0], g1[1], g1[2], g1[3]};
    size_t obase = ((size_t)b << 24) + ((size_t)i << 9) + j;
#pragma unroll
    for (int cc = 0; cc < 16; cc++) {
        int c = cg * 16 + cc;
        size_t oidx = obase + ((size_t)c << 18);
        float sv = o[cc] * invZ;
        __builtin_nontemporal_store(sv, &sapa[oidx]);
        float ev = pb[c];
#pragma unroll
        for (int u = 0; u < 8; u++) ev = fmaf(v8[u], pw[c * 8 + u], ev);
        unsigned int wbits = gu[cc >> 1];
        unsigned short hb = (cc & 1) ? (unsigned short)(wbits >> 16) : (unsigned short)(wbits & 0xffff);
        float gv = bf2f(hb);
        __builtin_nontemporal_store(gv * sv + (1.f - gv) * ev, &fin[oidx]);
    }
}

extern "C" void kernel_launch(void* const* d_in, const int* in_sizes, int n_in,
                              void* d_out, int out_size, void* d_ws, size_t ws_size,
                              hipStream_t stream) {
    const float* x = (const float*)d_in[0];
    const float* y = (const float*)d_in[1];
    const float* gate_w = (const float*)d_in[2];
    const float* gate_b = (const float*)d_in[3];
    const float* pc1a_w = (const float*)d_in[4];
    const float* pc1a_b = (const float*)d_in[5];
    const float* pc1b_w = (const float*)d_in[6];
    const float* pc1b_b = (const float*)d_in[7];
    const float* spa1_w = (const float*)d_in[8];
    const float* spa1_b = (const float*)d_in[9];
    const float* spa2_w = (const float*)d_in[10];
    const float* spa2_b = (const float*)d_in[11];
    const float* frq1_w = (const float*)d_in[12];
    const float* frq1_b = (const float*)d_in[13];
    const float* frq2_w = (const float*)d_in[14];
    const float* frq2_b = (const float*)d_in[15];
    const float* cat_w = (const float*)d_in[16];
    const float* cat_b = (const float*)d_in[17];
    const float* ca1_w = (const float*)d_in[18];
    const float* ca1_b = (const float*)d_in[19];
    const float* ca2_w = (const float*)d_in[20];
    const float* ca2_b = (const float*)d_in[21];
    const float* pc3_w = (const float*)d_in[22];
    const float* pc3_b = (const float*)d_in[23];
    const float* lny_g = (const float*)d_in[24];
    const float* lny_b = (const float*)d_in[25];
    const float* lnx_g = (const float*)d_in[26];
    const float* lnx_b = (const float*)d_in[27];
    const float* q_w = (const float*)d_in[28];
    const float* q_b = (const float*)d_in[29];
    const float* k_w = (const float*)d_in[30];
    const float* k_b = (const float*)d_in[31];

    float* out = (float*)d_out;
    float* finalp = out;
    float* sapap = out + 33554432;
    float* encp = out + 67108864;

    char* ws = (char*)d_ws;
    unsigned short* gate = (unsigned short*)ws;    // 67,108,864 B  [b][i][j][64] bf16
    unsigned short* f0 = (unsigned short*)(ws + 67108864);   // 16,777,216 B bf16 chlast
    unsigned short* f1 = (unsigned short*)(ws + 83886080);   // 16,777,216 B bf16
    unsigned short* tbuf = (unsigned short*)(ws + 100663296);// 16,777,216 B bf16
    float* f8 = (float*)(ws + 134217728);          // 16,777,216 B f32 [b][i][j][8]
    float* kbuf = (float*)(ws + 150994944);        // 8,388,608 B [b][h][w][64]
    float* xbuf = (float*)(ws + 159383552);        // 8,388,608 B
    float* partials = (float*)(ws + 167772160);    // 1,024 B
    float* cw = (float*)(ws + 167773184);          // 64 B
    float* wT5 = (float*)(ws + 167773248);         // 25,600 B [25][16][16]
    float* wT3a = (float*)(ws + 167798848);        // 9,216 B
    float* wT3b = (float*)(ws + 167808064);        // 9,216 B
    // glo/plo alias the tbuf region (dead until conv3r writes tbuf; consumed by k_gp first)
    float* glo = (float*)(ws + 100663296);         // 8,388,608 B
    float* plo = (float*)(ws + 109051904);         // 2,097,152 B
    // qbuf aliases f0+f1+tbuf regions (all dead after k_tail)
    unsigned short* qbuf = (unsigned short*)(ws + 67108864);  // 67,108,864 B

    dim3 blk(256);
    dim3 gridHi(2048);
    dim3 gridConv(2048);

    k_prep<<<dim3(25), blk, 0, stream>>>(pc1b_w, spa1_w, spa2_w, wT5, wT3a, wT3b);
    k_low<<<dim3(128), blk, 0, stream>>>(x, gate_w, gate_b, pc1a_w, lnx_g, lnx_b, k_w, k_b,
                                         kbuf, xbuf, glo, plo);
    k_gp<<<gridHi, blk, 0, stream>>>(glo, plo, y, pc1a_w, pc1a_b, gate, f0);
    k_conv5<<<gridConv, blk, 0, stream>>>(f0, wT5, pc1b_b, f1);
    k_conv3r<<<gridConv, blk, 0, stream>>>(f1, wT3a, spa1_b, tbuf);
    k_tail<<<gridConv, blk, 0, stream>>>(f1, tbuf, wT3b, spa2_b, frq1_w, frq1_b,
                                         frq2_w, frq2_b, cat_w, cat_b, f8);
    k_pool<<<dim3(32), blk, 0, stream>>>(f8, partials);
    k_se<<<dim3(1), dim3(64), 0, stream>>>(partials, ca1_w, ca1_b, ca2_w, ca2_b, cw);
    k_pc3<<<gridHi, blk, 0, stream>>>(f8, cw, pc3_w, pc3_b, lny_g, lny_b, q_w, q_b, encp, qbuf);
    k_attn<<<dim3(8192), blk, 0, stream>>>(f8, cw, pc3_w, pc3_b, gate, qbuf, kbuf, xbuf, sapap, finalp);
}

// Round 11
// 826.383 us; speedup vs baseline: 1.1595x; 1.1595x over previous
//
#include <hip/hip_runtime.h>
#include <hip/hip_bf16.h>
#include <math.h>

// B=2, C=64, 128x128 low-res, SCALE=4 -> 512x512, KUP=5, E=64
// d_out = [final | sapa | enc] each (2,64,512,512) f32

#define DEVFN static __device__ __forceinline__

typedef unsigned int u32x4 __attribute__((ext_vector_type(4)));

DEVFN float keys_w(float d) {
    if (d < 1.f) return ((1.5f * d - 2.5f) * d) * d + 1.f;
    if (d < 2.f) return ((-0.5f * d + 2.5f) * d - 4.f) * d + 2.f;
    return 0.f;
}

DEVFN void bicubic_axis(int o, int n, int idx4[4], float w4[4]) {
    // jax.image.resize 'cubic': sample=(o+0.5)/4-0.5, OOB taps dropped+renormalized
    float f = (o + 0.5f) * 0.25f - 0.5f;
    float fb = floorf(f);
    int ib = (int)fb;
    float t = f - fb;
    float ws[4];
    ws[0] = keys_w(1.f + t);
    ws[1] = keys_w(t);
    ws[2] = keys_w(1.f - t);
    ws[3] = keys_w(2.f - t);
    float s = 0.f;
#pragma unroll
    for (int m = 0; m < 4; m++) {
        int ix = ib - 1 + m;
        if (ix < 0 || ix >= n) ws[m] = 0.f;
        s += ws[m];
        idx4[m] = min(max(ix, 0), n - 1);
    }
    float inv = 1.f / s;
#pragma unroll
    for (int m = 0; m < 4; m++) w4[m] = ws[m] * inv;
}

DEVFN float sigm(float v) { return 1.f / (1.f + __expf(-v)); }

DEVFN unsigned short f2bf(float f) {
    __hip_bfloat16 h = __float2bfloat16(f);
    unsigned short u;
    __builtin_memcpy(&u, &h, 2);
    return u;
}
DEVFN float bf2f(unsigned short u) {
    union { unsigned int i; float f; } z;
    z.i = ((unsigned int)u) << 16;
    return z.f;
}

// ---------------- weight pre-transpose: w[oc][ic][tap] -> wT[tap][ic][oc] ----------------
__global__ __launch_bounds__(256) void k_prep(const float* __restrict__ w5,
                                              const float* __restrict__ w3a,
                                              const float* __restrict__ w3b,
                                              float* __restrict__ wT5,
                                              float* __restrict__ wT3a,
                                              float* __restrict__ wT3b) {
    int t = blockIdx.x * 256 + threadIdx.x;
    if (t < 6400) {
        int tap = t >> 8, ic = (t >> 4) & 15, oc = t & 15;
        wT5[t] = w5[(oc * 16 + ic) * 25 + tap];
    }
    if (t < 2304) {
        int tap = t >> 8, ic = (t >> 4) & 15, oc = t & 15;
        wT3a[t] = w3a[(oc * 16 + ic) * 9 + tap];
        wT3b[t] = w3b[(oc * 16 + ic) * 9 + tap];
    }
}

// ---------------- low-res fused: xbuf copy, k-proj, gate/pc1a projections ----------------
__global__ __launch_bounds__(256) void k_low(const float* __restrict__ x,
                                             const float* __restrict__ gw, const float* __restrict__ gb,
                                             const float* __restrict__ pw,
                                             const float* __restrict__ lg, const float* __restrict__ lb,
                                             const float* __restrict__ kw, const float* __restrict__ kbias,
                                             float* __restrict__ kb, float* __restrict__ xb,
                                             float* __restrict__ glo, float* __restrict__ plo) {
    int idx = blockIdx.x * 256 + threadIdx.x;  // 32768 px
    int w = idx & 127, h = (idx >> 7) & 127, b = idx >> 14;
    const float* xp = x + (size_t)b * 64 * 16384 + (h << 7) + w;
    float xv[64];
#pragma unroll
    for (int c = 0; c < 64; c++) xv[c] = xp[(size_t)c << 14];
    float4* xbp = (float4*)(xb + (size_t)idx * 64);
#pragma unroll
    for (int c4 = 0; c4 < 16; c4++)
        xbp[c4] = make_float4(xv[4 * c4], xv[4 * c4 + 1], xv[4 * c4 + 2], xv[4 * c4 + 3]);
    // gate projection on raw x (commutes with bicubic upsample)
    float4* gp = (float4*)(glo + (size_t)idx * 64);
#pragma unroll
    for (int e4 = 0; e4 < 16; e4++) {
        float r[4];
#pragma unroll
        for (int u = 0; u < 4; u++) {
            int e = e4 * 4 + u;
            float s = gb[e];
#pragma unroll
            for (int c = 0; c < 64; c++) s = fmaf(xv[c], gw[e * 64 + c], s);
            r[u] = s;
        }
        gp[e4] = make_float4(r[0], r[1], r[2], r[3]);
    }
    // pc1a x-part projection (bias + y-part added at hi-res)
    float4* pp = (float4*)(plo + (size_t)idx * 16);
#pragma unroll
    for (int e4 = 0; e4 < 4; e4++) {
        float r[4];
#pragma unroll
        for (int u = 0; u < 4; u++) {
            int e = e4 * 4 + u;
            float s = 0.f;
#pragma unroll
            for (int c = 0; c < 64; c++) s = fmaf(xv[c], pw[e * 67 + 3 + c], s);
            r[u] = s;
        }
        pp[e4] = make_float4(r[0], r[1], r[2], r[3]);
    }
    // layernorm + k projection
    float m = 0.f;
#pragma unroll
    for (int c = 0; c < 64; c++) m += xv[c];
    m *= (1.f / 64.f);
    float var = 0.f;
#pragma unroll
    for (int c = 0; c < 64; c++) {
        float d = xv[c] - m;
        var = fmaf(d, d, var);
    }
    var *= (1.f / 64.f);
    float rstd = rsqrtf(var + 1e-5f);
#pragma unroll
    for (int c = 0; c < 64; c++) xv[c] = (xv[c] - m) * rstd * lg[c] + lb[c];
    float4* kp = (float4*)(kb + (size_t)idx * 64);
#pragma unroll
    for (int e4 = 0; e4 < 16; e4++) {
        float r[4];
#pragma unroll
        for (int u = 0; u < 4; u++) {
            int e = e4 * 4 + u;
            float s = kbias[e];
#pragma unroll
            for (int c = 0; c < 64; c++) s = fmaf(xv[c], kw[e * 64 + c], s);
            r[u] = s;
        }
        kp[e4] = make_float4(r[0], r[1], r[2], r[3]);
    }
}

// ---------------- separable bicubic upsample of [g_lo(64)|p_lo(16)] -> gate bf16 chlast + f0 chlast ----------------
__global__ __launch_bounds__(256) void k_gp(const float* __restrict__ glo, const float* __restrict__ plo,
                                            const float* __restrict__ y,
                                            const float* __restrict__ paw, const float* __restrict__ pab,
                                            __hip_bfloat16* __restrict__ gate, float* __restrict__ f0) {
    __shared__ float v[68 * 81];  // [col][ch], stride 81 to spread banks
    int bid = blockIdx.x;
    int b = bid >> 10, i = (bid >> 1) & 511, j0 = (bid & 1) << 8;
    int t = threadIdx.x;
    int iy[4];
    float wy[4];
    bicubic_axis(i, 128, iy, wy);
    int c0 = (j0 >> 2) - 2;
    // vertical pass into LDS
    for (int e = t; e < 68 * 80; e += 256) {
        int ch = e % 80, lc = e / 80;
        int gc = c0 + lc;
        float val = 0.f;
        if ((unsigned)gc < 128u) {
            if (ch < 64) {
                val = wy[0] * glo[(size_t)((b * 128 + iy[0]) * 128 + gc) * 64 + ch] +
                      wy[1] * glo[(size_t)((b * 128 + iy[1]) * 128 + gc) * 64 + ch] +
                      wy[2] * glo[(size_t)((b * 128 + iy[2]) * 128 + gc) * 64 + ch] +
                      wy[3] * glo[(size_t)((b * 128 + iy[3]) * 128 + gc) * 64 + ch];
            } else {
                int cc = ch - 64;
                val = wy[0] * plo[(size_t)((b * 128 + iy[0]) * 128 + gc) * 16 + cc] +
                      wy[1] * plo[(size_t)((b * 128 + iy[1]) * 128 + gc) * 16 + cc] +
                      wy[2] * plo[(size_t)((b * 128 + iy[2]) * 128 + gc) * 16 + cc] +
                      wy[3] * plo[(size_t)((b * 128 + iy[3]) * 128 + gc) * 16 + cc];
            }
        }
        v[lc * 81 + ch] = val;
    }
    __syncthreads();
    // horizontal pass: one px per thread
    int j = j0 + t;
    int jx[4];
    float wx[4];
    bicubic_axis(j, 128, jx, wx);
    int lx0 = jx[0] - c0, lx1 = jx[1] - c0, lx2 = jx[2] - c0, lx3 = jx[3] - c0;
    float out[80];
#pragma unroll
    for (int ch = 0; ch < 80; ch++)
        out[ch] = wx[0] * v[lx0 * 81 + ch] + wx[1] * v[lx1 * 81 + ch] +
                  wx[2] * v[lx2 * 81 + ch] + wx[3] * v[lx3 * 81 + ch];
    size_t pxoff = ((size_t)b << 18) + ((size_t)i << 9) + j;
    // gate: sigmoid -> bf16 packed stores (ALL 64 channels)
    unsigned int uu[32];
#pragma unroll
    for (int k = 0; k < 32; k++) {
        unsigned short h0 = f2bf(sigm(out[2 * k]));
        unsigned short h1 = f2bf(sigm(out[2 * k + 1]));
        uu[k] = (unsigned int)h0 | ((unsigned int)h1 << 16);
    }
    uint4* gp4 = (uint4*)((unsigned short*)gate + pxoff * 64);
#pragma unroll
    for (int k4 = 0; k4 < 8; k4++)
        gp4[k4] = make_uint4(uu[4 * k4], uu[4 * k4 + 1], uu[4 * k4 + 2], uu[4 * k4 + 3]);
    // f0 = up(p_lo) + W_y*y + b
    float yc0 = y[((size_t)(b * 3 + 0) << 18) + ((size_t)i << 9) + j];
    float yc1 = y[((size_t)(b * 3 + 1) << 18) + ((size_t)i << 9) + j];
    float yc2 = y[((size_t)(b * 3 + 2) << 18) + ((size_t)i << 9) + j];
    float4* fp = (float4*)(f0 + pxoff * 16);
#pragma unroll
    for (int e4 = 0; e4 < 4; e4++) {
        float r[4];
#pragma unroll
        for (int u = 0; u < 4; u++) {
            int oc = e4 * 4 + u;
            r[u] = out[64 + oc] + pab[oc] + yc0 * paw[oc * 67 + 0] + yc1 * paw[oc * 67 + 1] + yc2 * paw[oc * 67 + 2];
        }
        fp[e4] = make_float4(r[0], r[1], r[2], r[3]);
    }
}

// ---------------- 5x5 conv 16->16 pad2, LDS-staged tile, channel-last ----------------
__global__ __launch_bounds__(256) void k_conv5(const float* __restrict__ fin,
                                               const float* __restrict__ wT,
                                               const float* __restrict__ bias,
                                               float* __restrict__ fout) {
    __shared__ float lds[8 * 68 * 20];  // 43,520 B
    int tid = threadIdx.x;
    int bid = blockIdx.x;  // 2048 = 2 * 128 * 8
    int seg = bid & 7, it = (bid >> 3) & 127, b = bid >> 10;
    int i0 = it * 4, j0 = seg * 64;
    for (int s = tid; s < 2176; s += 256) {  // 8*68 px * 4 parts
        int part = s & 3, px = s >> 2;
        int row = px / 68, col = px - row * 68;
        int gi = i0 - 2 + row, gj = j0 - 2 + col;
        float4 v = make_float4(0.f, 0.f, 0.f, 0.f);
        if ((unsigned)gi < 512u && (unsigned)gj < 512u)
            v = *(const float4*)(fin + (((size_t)b << 18) + ((size_t)gi << 9) + gj) * 16 + part * 4);
        *(float4*)(&lds[(row * 68 + col) * 20 + part * 4]) = v;
    }
    __syncthreads();
    int tx = tid & 63, ty = tid >> 6;
    float acc[16];
#pragma unroll
    for (int oc = 0; oc < 16; oc++) acc[oc] = bias[oc];
#pragma unroll
    for (int ky = 0; ky < 5; ky++) {
#pragma unroll
        for (int kx = 0; kx < 5; kx++) {
            const float* p = &lds[((ty + ky) * 68 + tx + kx) * 20];
            float vv[16];
            *(float4*)(vv + 0) = *(const float4*)(p + 0);
            *(float4*)(vv + 4) = *(const float4*)(p + 4);
            *(float4*)(vv + 8) = *(const float4*)(p + 8);
            *(float4*)(vv + 12) = *(const float4*)(p + 12);
            const float* wp = wT + (ky * 5 + kx) * 256;
#pragma unroll
            for (int ic = 0; ic < 16; ic++) {
                float v = vv[ic];
#pragma unroll
                for (int oc = 0; oc < 16; oc++)
                    acc[oc] = fmaf(v, wp[ic * 16 + oc], acc[oc]);
            }
        }
    }
    int i = i0 + ty, j = j0 + tx;
    float4* op = (float4*)(fout + (((size_t)b << 18) + ((size_t)i << 9) + j) * 16);
    op[0] = make_float4(acc[0], acc[1], acc[2], acc[3]);
    op[1] = make_float4(acc[4], acc[5], acc[6], acc[7]);
    op[2] = make_float4(acc[8], acc[9], acc[10], acc[11]);
    op[3] = make_float4(acc[12], acc[13], acc[14], acc[15]);
}

// ---------------- 3x3 conv 16->16 pad1 + relu, LDS-staged ----------------
__global__ __launch_bounds__(256) void k_conv3r(const float* __restrict__ fin,
                                                const float* __restrict__ wT,
                                                const float* __restrict__ bias,
                                                float* __restrict__ fout) {
    __shared__ float lds[6 * 66 * 20];  // 31,680 B
    int tid = threadIdx.x;
    int bid = blockIdx.x;
    int seg = bid & 7, it = (bid >> 3) & 127, b = bid >> 10;
    int i0 = it * 4, j0 = seg * 64;
    for (int s = tid; s < 1584; s += 256) {  // 6*66 px * 4 parts
        int part = s & 3, px = s >> 2;
        int row = px / 66, col = px - row * 66;
        int gi = i0 - 1 + row, gj = j0 - 1 + col;
        float4 v = make_float4(0.f, 0.f, 0.f, 0.f);
        if ((unsigned)gi < 512u && (unsigned)gj < 512u)
            v = *(const float4*)(fin + (((size_t)b << 18) + ((size_t)gi << 9) + gj) * 16 + part * 4);
        *(float4*)(&lds[(row * 66 + col) * 20 + part * 4]) = v;
    }
    __syncthreads();
    int tx = tid & 63, ty = tid >> 6;
    float acc[16];
#pragma unroll
    for (int oc = 0; oc < 16; oc++) acc[oc] = bias[oc];
#pragma unroll
    for (int ky = 0; ky < 3; ky++) {
#pragma unroll
        for (int kx = 0; kx < 3; kx++) {
            const float* p = &lds[((ty + ky) * 66 + tx + kx) * 20];
            float vv[16];
            *(float4*)(vv + 0) = *(const float4*)(p + 0);
            *(float4*)(vv + 4) = *(const float4*)(p + 4);
            *(float4*)(vv + 8) = *(const float4*)(p + 8);
            *(float4*)(vv + 12) = *(const float4*)(p + 12);
            const float* wp = wT + (ky * 3 + kx) * 256;
#pragma unroll
            for (int ic = 0; ic < 16; ic++) {
                float v = vv[ic];
#pragma unroll
                for (int oc = 0; oc < 16; oc++)
                    acc[oc] = fmaf(v, wp[ic * 16 + oc], acc[oc]);
            }
        }
    }
    int i = i0 + ty, j = j0 + tx;
    float4* op = (float4*)(fout + (((size_t)b << 18) + ((size_t)i << 9) + j) * 16);
    op[0] = make_float4(fmaxf(acc[0], 0.f), fmaxf(acc[1], 0.f), fmaxf(acc[2], 0.f), fmaxf(acc[3], 0.f));
    op[1] = make_float4(fmaxf(acc[4], 0.f), fmaxf(acc[5], 0.f), fmaxf(acc[6], 0.f), fmaxf(acc[7], 0.f));
    op[2] = make_float4(fmaxf(acc[8], 0.f), fmaxf(acc[9], 0.f), fmaxf(acc[10], 0.f), fmaxf(acc[11], 0.f));
    op[3] = make_float4(fmaxf(acc[12], 0.f), fmaxf(acc[13], 0.f), fmaxf(acc[14], 0.f), fmaxf(acc[15], 0.f));
}

// ---------------- spa2(t)+f1 residual, frq chain, cat -> f8 (LDS-staged 3x3) ----------------
__global__ __launch_bounds__(256) void k_tail(const float* __restrict__ f1,
                                              const float* __restrict__ t,
                                              const float* __restrict__ wT2,
                                              const float* __restrict__ s2b,
                                              const float* __restrict__ q1w, const float* __restrict__ q1b,
                                              const float* __restrict__ q2w, const float* __restrict__ q2b,
                                              const float* __restrict__ cw_, const float* __restrict__ cb_,
                                              float* __restrict__ f8) {
    __shared__ float lds[6 * 66 * 20];
    int tid = threadIdx.x;
    int bid = blockIdx.x;
    int seg = bid & 7, it = (bid >> 3) & 127, b = bid >> 10;
    int i0 = it * 4, j0 = seg * 64;
    for (int s = tid; s < 1584; s += 256) {
        int part = s & 3, px = s >> 2;
        int row = px / 66, col = px - row * 66;
        int gi = i0 - 1 + row, gj = j0 - 1 + col;
        float4 v = make_float4(0.f, 0.f, 0.f, 0.f);
        if ((unsigned)gi < 512u && (unsigned)gj < 512u)
            v = *(const float4*)(t + (((size_t)b << 18) + ((size_t)gi << 9) + gj) * 16 + part * 4);
        *(float4*)(&lds[(row * 66 + col) * 20 + part * 4]) = v;
    }
    __syncthreads();
    int tx = tid & 63, ty = tid >> 6;
    int i = i0 + ty, j = j0 + tx;
    float sp[16];
#pragma unroll
    for (int oc = 0; oc < 16; oc++) sp[oc] = s2b[oc];
#pragma unroll
    for (int ky = 0; ky < 3; ky++) {
#pragma unroll
        for (int kx = 0; kx < 3; kx++) {
            const float* p = &lds[((ty + ky) * 66 + tx + kx) * 20];
            float vv[16];
            *(float4*)(vv + 0) = *(const float4*)(p + 0);
            *(float4*)(vv + 4) = *(const float4*)(p + 4);
            *(float4*)(vv + 8) = *(const float4*)(p + 8);
            *(float4*)(vv + 12) = *(const float4*)(p + 12);
            const float* wp = wT2 + (ky * 3 + kx) * 256;
#pragma unroll
            for (int ic = 0; ic < 16; ic++) {
                float v = vv[ic];
#pragma unroll
                for (int oc = 0; oc < 16; oc++)
                    sp[oc] = fmaf(v, wp[ic * 16 + oc], sp[oc]);
            }
        }
    }
    // own-pixel f1 (residual + frq input)
    float fv[16];
    const float4* f1p = (const float4*)(f1 + (((size_t)b << 18) + ((size_t)i << 9) + j) * 16);
    *(float4*)(fv + 0) = f1p[0];
    *(float4*)(fv + 4) = f1p[1];
    *(float4*)(fv + 8) = f1p[2];
    *(float4*)(fv + 12) = f1p[3];
#pragma unroll
    for (int c = 0; c < 16; c++) sp[c] += fv[c];
    float mid[16];
#pragma unroll
    for (int r = 0; r < 16; r++) {
        float m = q1b[r];
#pragma unroll
        for (int c = 0; c < 16; c++) m = fmaf(fv[c], q1w[r * 16 + c], m);
        mid[r] = fmaxf(m, 0.f);
    }
    float fo[16];
#pragma unroll
    for (int r = 0; r < 16; r++) {
        float m = q2b[r];
#pragma unroll
        for (int c = 0; c < 16; c++) m = fmaf(mid[c], q2w[r * 16 + c], m);
        fo[r] = m;
    }
    float r8[8];
#pragma unroll
    for (int o = 0; o < 8; o++) {
        float a = cb_[o];
#pragma unroll
        for (int c = 0; c < 16; c++) a = fmaf(sp[c], cw_[o * 32 + c], a);
#pragma unroll
        for (int c = 0; c < 16; c++) a = fmaf(fo[c], cw_[o * 32 + 16 + c], a);
        r8[o] = a;
    }
    float4* op = (float4*)(f8 + (((size_t)b << 18) + ((size_t)i << 9) + j) * 8);
    op[0] = make_float4(r8[0], r8[1], r8[2], r8[3]);
    op[1] = make_float4(r8[4], r8[5], r8[6], r8[7]);
}

// ---------------- pooled mean partials (channel-last f8) ----------------
__global__ __launch_bounds__(256) void k_pool(const float* __restrict__ f8, float* __restrict__ partials) {
    int b = blockIdx.x >> 4, blk = blockIdx.x & 15;
    const float4* fp = (const float4*)(f8 + (((size_t)b) << 18) * 8);
    float acc[8];
#pragma unroll
    for (int c = 0; c < 8; c++) acc[c] = 0.f;
    int p0 = blk * 16384;
    for (int p = p0 + threadIdx.x; p < p0 + 16384; p += 256) {
        float4 a0 = fp[p * 2], a1 = fp[p * 2 + 1];
        acc[0] += a0.x; acc[1] += a0.y; acc[2] += a0.z; acc[3] += a0.w;
        acc[4] += a1.x; acc[5] += a1.y; acc[6] += a1.z; acc[7] += a1.w;
    }
#pragma unroll
    for (int off = 32; off; off >>= 1) {
#pragma unroll
        for (int c = 0; c < 8; c++) acc[c] += __shfl_down(acc[c], off, 64);
    }
    __shared__ float ls[4][8];
    int lane = threadIdx.x & 63, wv = threadIdx.x >> 6;
    if (lane == 0) {
#pragma unroll
        for (int c = 0; c < 8; c++) ls[wv][c] = acc[c];
    }
    __syncthreads();
    if (threadIdx.x < 8) {
        float s = ls[0][threadIdx.x] + ls[1][threadIdx.x] + ls[2][threadIdx.x] + ls[3][threadIdx.x];
        partials[(b * 8 + threadIdx.x) * 16 + blk] = s;
    }
}

__global__ void k_se(const float* __restrict__ partials,
                     const float* __restrict__ w1, const float* __restrict__ b1,
                     const float* __restrict__ w2, const float* __restrict__ b2,
                     float* __restrict__ cw) {
    int b = threadIdx.x;
    if (b >= 2) return;
    float pooled[8];
#pragma unroll
    for (int c = 0; c < 8; c++) {
        float s = 0.f;
#pragma unroll
        for (int k = 0; k < 16; k++) s += partials[(b * 8 + c) * 16 + k];
        pooled[c] = s * (1.f / 262144.f);
    }
    float mid[2];
#pragma unroll
    for (int r = 0; r < 2; r++) {
        float m = b1[r];
#pragma unroll
        for (int c = 0; c < 8; c++) m = fmaf(w1[r * 8 + c], pooled[c], m);
        mid[r] = fmaxf(m, 0.f);
    }
#pragma unroll
    for (int c = 0; c < 8; c++) {
        float v = b2[c] + w2[c * 2 + 0] * mid[0] + w2[c * 2 + 1] * mid[1];
        cw[b * 8 + c] = 1.f / (1.f + __expf(-v));
    }
}

// ---------------- enc = conv1x1_8->64(f8*cw) + fused LN(lny) + q-proj -> qbuf bf16 chlast ----------------
__global__ __launch_bounds__(256) void k_pc3(const float* __restrict__ f8, const float* __restrict__ cw,
                                             const float* __restrict__ w, const float* __restrict__ bias,
                                             const float* __restrict__ lg, const float* __restrict__ lb,
                                             const float* __restrict__ qw, const float* __restrict__ qbias,
                                             float* __restrict__ enc, unsigned short* __restrict__ qbuf) {
    int idx = blockIdx.x * 256 + threadIdx.x;
    int b = idx >> 18;
    size_t hi = (size_t)idx & 262143;
    const float4* fp = (const float4*)(f8 + (size_t)idx * 8);
    float4 a0 = fp[0], a1 = fp[1];
    float v[8] = {a0.x, a0.y, a0.z, a0.w, a1.x, a1.y, a1.z, a1.w};
#pragma unroll
    for (int c = 0; c < 8; c++) v[c] *= cw[b * 8 + c];
    float yn[64];
#pragma unroll
    for (int oc = 0; oc < 64; oc++) {
        float a = bias[oc];
#pragma unroll
        for (int c = 0; c < 8; c++) a = fmaf(v[c], w[oc * 8 + c], a);
        yn[oc] = a;
        enc[((size_t)(b * 64 + oc) << 18) + hi] = a;
    }
    // layernorm (lny) over the 64 channels (all in regs)
    float m = 0.f;
#pragma unroll
    for (int c = 0; c < 64; c++) m += yn[c];
    m *= (1.f / 64.f);
    float var = 0.f;
#pragma unroll
    for (int c = 0; c < 64; c++) {
        float d = yn[c] - m;
        var = fmaf(d, d, var);
    }
    var *= (1.f / 64.f);
    float rstd = rsqrtf(var + 1e-5f);
#pragma unroll
    for (int c = 0; c < 64; c++) yn[c] = (yn[c] - m) * rstd * lg[c] + lb[c];
    // q projection (wave-uniform weight reads -> s_load), store bf16 channel-last
    unsigned short* qp = qbuf + (size_t)idx * 64;
    for (int e0 = 0; e0 < 64; e0 += 8) {
        float qv[8];
#pragma unroll
        for (int u = 0; u < 8; u++) {
            float s = qbias[e0 + u];
#pragma unroll
            for (int c = 0; c < 64; c++) s = fmaf(yn[c], qw[(e0 + u) * 64 + c], s);
            qv[u] = s;
        }
        unsigned int pk[4];
#pragma unroll
        for (int u = 0; u < 4; u++)
            pk[u] = (unsigned int)f2bf(qv[2 * u]) | ((unsigned int)f2bf(qv[2 * u + 1]) << 16);
        *(uint4*)(qp + e0) = make_uint4(pk[0], pk[1], pk[2], pk[3]);
    }
}

// ---------------- attention + blend: row-tile (1 i x 64 j), 4 threads/pixel ----------------
// Wave lanes for a fixed channel cover 16 consecutive j -> all planar accesses are full
// 64B segments. K and X halos (5x20 low-res pts) time-share one LDS buffer.
__global__ __launch_bounds__(256, 4) void k_attn(const float* __restrict__ enc,
                                                 const __hip_bfloat16* __restrict__ gate,
                                                 const unsigned short* __restrict__ qb,
                                                 const float* __restrict__ kb, const float* __restrict__ xbv,
                                                 float* __restrict__ sapa, float* __restrict__ fin) {
    __shared__ float tile[100 * 68];  // 27,200 B, stride 68 -> <=2-way bank overlap (free)
    int tid = threadIdx.x;
    int bid = blockIdx.x;  // 2 * 512 * 8
    int b = bid >> 12, i = (bid >> 3) & 511, jb = bid & 7;
    int j0 = jb << 6;
    int h = i >> 2;          // low-res row (fixed for the whole block)
    int wbase = j0 >> 2;     // first low-res col of the tile
    int cg = tid & 3, px = tid >> 2;
    int j = j0 + px;
    size_t pix = ((size_t)b << 18) + ((size_t)i << 9) + j;
    // this thread's 16 q-components (e-group = cg), bf16 channel-last (nontemporal: read-once)
    const u32x4* qp = (const u32x4*)(qb + pix * 64 + cg * 16);
    u32x4 q0 = __builtin_nontemporal_load(qp), q1 = __builtin_nontemporal_load(qp + 1);
    unsigned int qu[8] = {q0[0], q0[1], q0[2], q0[3], q1[0], q1[1], q1[2], q1[3]};
    float q[16];
#pragma unroll
    for (int k = 0; k < 8; k++) {
        q[2 * k] = bf2f((unsigned short)(qu[k] & 0xffff));
        q[2 * k + 1] = bf2f((unsigned short)(qu[k] >> 16));
    }
    // ---- phase 1: stage K halo (5 rows x 20 cols), zero-filled OOB ----
    for (int s = tid; s < 1600; s += 256) {
        int p = s >> 4, e4 = s & 15;
        int row = p / 20, col = p - row * 20;
        int hh = h - 2 + row, ww = wbase - 2 + col;
        float4 val = make_float4(0.f, 0.f, 0.f, 0.f);
        if ((unsigned)hh < 128u && (unsigned)ww < 128u)
            val = ((const float4*)(kb + (size_t)((b * 128 + hh) * 128 + ww) * 64))[e4];
        *(float4*)(tile + p * 68 + e4 * 4) = val;
    }
    __syncthreads();
    // ---- QK partial logits over my 16 e's ----
    int wl = px >> 2;  // 0..15 local low-res col
    float a[25];
#pragma unroll
    for (int dy = 0; dy < 5; dy++) {
#pragma unroll
        for (int dx = 0; dx < 5; dx++) {
            int lp = dy * 20 + wl + dx;
            const float4* kp = (const float4*)(tile + lp * 68 + cg * 16);
            float s = 0.f;
#pragma unroll
            for (int e4 = 0; e4 < 4; e4++) {
                float4 kv = kp[e4];
                s = fmaf(q[4 * e4 + 0], kv.x, s);
                s = fmaf(q[4 * e4 + 1], kv.y, s);
                s = fmaf(q[4 * e4 + 2], kv.z, s);
                s = fmaf(q[4 * e4 + 3], kv.w, s);
            }
            a[dy * 5 + dx] = s;
        }
    }
    // quad reduce (4 threads of one pixel are consecutive lanes)
#pragma unroll
    for (int p = 0; p < 25; p++) {
        a[p] += __shfl_xor(a[p], 1, 4);
        a[p] += __shfl_xor(a[p], 2, 4);
    }
    // softmax (replicated x4, cheap; OOB taps have exact 0 logit)
    float mx = a[0];
#pragma unroll
    for (int p = 1; p < 25; p++) mx = fmaxf(mx, a[p]);
    float Z = 0.f;
#pragma unroll
    for (int p = 0; p < 25; p++) {
        a[p] = __expf(a[p] - mx);
        Z += a[p];
    }
    float invZ = 1.f / Z;
    __syncthreads();  // all QK reads done before overwriting tile
    // ---- phase 2: stage X halo into the same buffer ----
    for (int s = tid; s < 1600; s += 256) {
        int p = s >> 4, e4 = s & 15;
        int row = p / 20, col = p - row * 20;
        int hh = h - 2 + row, ww = wbase - 2 + col;
        float4 val = make_float4(0.f, 0.f, 0.f, 0.f);
        if ((unsigned)hh < 128u && (unsigned)ww < 128u)
            val = ((const float4*)(xbv + (size_t)((b * 128 + hh) * 128 + ww) * 64))[e4];
        *(float4*)(tile + p * 68 + e4 * 4) = val;
    }
    __syncthreads();
    // ---- PV over my 16 channels ----
    float o[16];
#pragma unroll
    for (int k = 0; k < 16; k++) o[k] = 0.f;
#pragma unroll
    for (int dy = 0; dy < 5; dy++) {
#pragma unroll
        for (int dx = 0; dx < 5; dx++) {
            float wp = a[dy * 5 + dx];
            int lp = dy * 20 + wl + dx;
            const float4* xp = (const float4*)(tile + lp * 68 + cg * 16);
#pragma unroll
            for (int e4 = 0; e4 < 4; e4++) {
                float4 xv = xp[e4];
                o[4 * e4 + 0] = fmaf(wp, xv.x, o[4 * e4 + 0]);
                o[4 * e4 + 1] = fmaf(wp, xv.y, o[4 * e4 + 1]);
                o[4 * e4 + 2] = fmaf(wp, xv.z, o[4 * e4 + 2]);
                o[4 * e4 + 3] = fmaf(wp, xv.w, o[4 * e4 + 3]);
            }
        }
    }
    // ---- epilogue: gate (chlast bf16, nontemporal), enc read + sapa/fin nontemporal writes ----
    const u32x4* gp4 = (const u32x4*)((const unsigned short*)gate + pix * 64 + cg * 16);
    u32x4 g0 = __builtin_nontemporal_load(gp4), g1 = __builtin_nontemporal_load(gp4 + 1);
    unsigned int gu[8] = {g0[0], g0[1], g0[2], g0[3], g1[0], g1[1], g1[2], g1[3]};
    size_t obase = ((size_t)b << 24) + ((size_t)i << 9) + j;
    const float* ep = enc + obase;
#pragma unroll
    for (int cc = 0; cc < 16; cc++) {
        int c = cg * 16 + cc;
        size_t oidx = obase + ((size_t)c << 18);
        float sv = o[cc] * invZ;
        __builtin_nontemporal_store(sv, &sapa[oidx]);
        unsigned int wbits = gu[cc >> 1];
        unsigned short hb = (cc & 1) ? (unsigned short)(wbits >> 16) : (unsigned short)(wbits & 0xffff);
        float gv = bf2f(hb);
        float ev = ep[(size_t)c << 18];
        __builtin_nontemporal_store(gv * sv + (1.f - gv) * ev, &fin[oidx]);
    }
}

extern "C" void kernel_launch(void* const* d_in, const int* in_sizes, int n_in,
                              void* d_out, int out_size, void* d_ws, size_t ws_size,
                              hipStream_t stream) {
    const float* x = (const float*)d_in[0];
    const float* y = (const float*)d_in[1];
    const float* gate_w = (const float*)d_in[2];
    const float* gate_b = (const float*)d_in[3];
    const float* pc1a_w = (const float*)d_in[4];
    const float* pc1a_b = (const float*)d_in[5];
    const float* pc1b_w = (const float*)d_in[6];
    const float* pc1b_b = (const float*)d_in[7];
    const float* spa1_w = (const float*)d_in[8];
    const float* spa1_b = (const float*)d_in[9];
    const float* spa2_w = (const float*)d_in[10];
    const float* spa2_b = (const float*)d_in[11];
    const float* frq1_w = (const float*)d_in[12];
    const float* frq1_b = (const float*)d_in[13];
    const float* frq2_w = (const float*)d_in[14];
    const float* frq2_b = (const float*)d_in[15];
    const float* cat_w = (const float*)d_in[16];
    const float* cat_b = (const float*)d_in[17];
    const float* ca1_w = (const float*)d_in[18];
    const float* ca1_b = (const float*)d_in[19];
    const float* ca2_w = (const float*)d_in[20];
    const float* ca2_b = (const float*)d_in[21];
    const float* pc3_w = (const float*)d_in[22];
    const float* pc3_b = (const float*)d_in[23];
    const float* lny_g = (const float*)d_in[24];
    const float* lny_b = (const float*)d_in[25];
    const float* lnx_g = (const float*)d_in[26];
    const float* lnx_b = (const float*)d_in[27];
    const float* q_w = (const float*)d_in[28];
    const float* q_b = (const float*)d_in[29];
    const float* k_w = (const float*)d_in[30];
    const float* k_b = (const float*)d_in[31];

    float* out = (float*)d_out;
    float* finalp = out;
    float* sapap = out + 33554432;
    float* encp = out + 67108864;

    char* ws = (char*)d_ws;
    __hip_bfloat16* gate = (__hip_bfloat16*)ws;   // 67,108,864 B  [b][i][j][64] bf16
    float* f0 = (float*)(ws + 67108864);          // 33,554,432 B  [b][i][j][16]
    float* f1 = (float*)(ws + 100663296);         // 33,554,432 B  [b][i][j][16]
    float* f8 = (float*)(ws + 134217728);         // 16,777,216 B  [b][i][j][8]
    float* kbuf = (float*)(ws + 150994944);       // 8,388,608 B   [b][h][w][64]
    float* xbuf = (float*)(ws + 159383552);       // 8,388,608 B   [b][h][w][64]
    float* partials = (float*)(ws + 167772160);   // 1,024 B
    float* cw = (float*)(ws + 167773184);         // 64 B
    float* wT5 = (float*)(ws + 167773248);        // 25,600 B [25][16][16]
    float* wT3a = (float*)(ws + 167798848);       // 9,216 B  [9][16][16]
    float* wT3b = (float*)(ws + 167808064);       // 9,216 B  [9][16][16]
    // aliases: g_lo/p_lo live in f1 region (consumed by k_gp before conv5 writes f1)
    float* glo = f1;                               // 8,388,608 B [b][h][w][64]
    float* plo = f1 + 2097152;                     // 2,097,152 B [b][h][w][16]
    float* tbuf = f0;                              // reuse f0 after conv5 consumed it
    // qbuf aliases f0+f1 (both dead after k_tail; k_pc3 writes it, k_attn reads it)
    unsigned short* qbuf = (unsigned short*)(ws + 67108864);  // 67,108,864 B [b][i][j][64] bf16

    dim3 blk(256);
    dim3 gridHi(2048);
    dim3 gridConv(2048);  // 2 x 128 i-tiles x 8 col-segments

    k_prep<<<dim3(25), blk, 0, stream>>>(pc1b_w, spa1_w, spa2_w, wT5, wT3a, wT3b);
    k_low<<<dim3(128), blk, 0, stream>>>(x, gate_w, gate_b, pc1a_w, lnx_g, lnx_b, k_w, k_b,
                                         kbuf, xbuf, glo, plo);
    k_gp<<<gridHi, blk, 0, stream>>>(glo, plo, y, pc1a_w, pc1a_b, gate, f0);
    k_conv5<<<gridConv, blk, 0, stream>>>(f0, wT5, pc1b_b, f1);
    k_conv3r<<<gridConv, blk, 0, stream>>>(f1, wT3a, spa1_b, tbuf);
    k_tail<<<gridConv, blk, 0, stream>>>(f1, tbuf, wT3b, spa2_b, frq1_w, frq1_b,
                                         frq2_w, frq2_b, cat_w, cat_b, f8);
    k_pool<<<dim3(32), blk, 0, stream>>>(f8, partials);
    k_se<<<dim3(1), dim3(64), 0, stream>>>(partials, ca1_w, ca1_b, ca2_w, ca2_b, cw);
    k_pc3<<<gridHi, blk, 0, stream>>>(f8, cw, pc3_w, pc3_b, lny_g, lny_b, q_w, q_b, encp, qbuf);
    k_attn<<<dim3(8192), blk, 0, stream>>>(encp, gate, qbuf, kbuf, xbuf, sapap, finalp);
}

// Round 12
// 821.087 us; speedup vs baseline: 1.1670x; 1.0064x over previous
//
#include <hip/hip_runtime.h>
#include <hip/hip_bf16.h>
#include <math.h>

// B=2, C=64, 128x128 low-res, SCALE=4 -> 512x512, KUP=5, E=64
// d_out = [final | sapa | enc] each (2,64,512,512) f32

#define DEVFN static __device__ __forceinline__

typedef unsigned int u32x4 __attribute__((ext_vector_type(4)));

DEVFN float keys_w(float d) {
    if (d < 1.f) return ((1.5f * d - 2.5f) * d) * d + 1.f;
    if (d < 2.f) return ((-0.5f * d + 2.5f) * d - 4.f) * d + 2.f;
    return 0.f;
}

DEVFN void bicubic_axis(int o, int n, int idx4[4], float w4[4]) {
    // jax.image.resize 'cubic': sample=(o+0.5)/4-0.5, OOB taps dropped+renormalized
    float f = (o + 0.5f) * 0.25f - 0.5f;
    float fb = floorf(f);
    int ib = (int)fb;
    float t = f - fb;
    float ws[4];
    ws[0] = keys_w(1.f + t);
    ws[1] = keys_w(t);
    ws[2] = keys_w(1.f - t);
    ws[3] = keys_w(2.f - t);
    float s = 0.f;
#pragma unroll
    for (int m = 0; m < 4; m++) {
        int ix = ib - 1 + m;
        if (ix < 0 || ix >= n) ws[m] = 0.f;
        s += ws[m];
        idx4[m] = min(max(ix, 0), n - 1);
    }
    float inv = 1.f / s;
#pragma unroll
    for (int m = 0; m < 4; m++) w4[m] = ws[m] * inv;
}

DEVFN float sigm(float v) { return 1.f / (1.f + __expf(-v)); }

DEVFN unsigned short f2bf(float f) {
    __hip_bfloat16 h = __float2bfloat16(f);
    unsigned short u;
    __builtin_memcpy(&u, &h, 2);
    return u;
}
DEVFN float bf2f(unsigned short u) {
    union { unsigned int i; float f; } z;
    z.i = ((unsigned int)u) << 16;
    return z.f;
}

// ---------------- weight pre-transpose: w[oc][ic][tap] -> wT[tap][ic][oc] ----------------
__global__ __launch_bounds__(256) void k_prep(const float* __restrict__ w5,
                                              const float* __restrict__ w3a,
                                              const float* __restrict__ w3b,
                                              float* __restrict__ wT5,
                                              float* __restrict__ wT3a,
                                              float* __restrict__ wT3b) {
    int t = blockIdx.x * 256 + threadIdx.x;
    if (t < 6400) {
        int tap = t >> 8, ic = (t >> 4) & 15, oc = t & 15;
        wT5[t] = w5[(oc * 16 + ic) * 25 + tap];
    }
    if (t < 2304) {
        int tap = t >> 8, ic = (t >> 4) & 15, oc = t & 15;
        wT3a[t] = w3a[(oc * 16 + ic) * 9 + tap];
        wT3b[t] = w3b[(oc * 16 + ic) * 9 + tap];
    }
}

// ---------------- low-res fused: xbuf copy, k-proj, gate/pc1a projections ----------------
__global__ __launch_bounds__(256) void k_low(const float* __restrict__ x,
                                             const float* __restrict__ gw, const float* __restrict__ gb,
                                             const float* __restrict__ pw,
                                             const float* __restrict__ lg, const float* __restrict__ lb,
                                             const float* __restrict__ kw, const float* __restrict__ kbias,
                                             float* __restrict__ kb, float* __restrict__ xb,
                                             float* __restrict__ glo, float* __restrict__ plo) {
    int idx = blockIdx.x * 256 + threadIdx.x;  // 32768 px
    int w = idx & 127, h = (idx >> 7) & 127, b = idx >> 14;
    const float* xp = x + (size_t)b * 64 * 16384 + (h << 7) + w;
    float xv[64];
#pragma unroll
    for (int c = 0; c < 64; c++) xv[c] = xp[(size_t)c << 14];
    float4* xbp = (float4*)(xb + (size_t)idx * 64);
#pragma unroll
    for (int c4 = 0; c4 < 16; c4++)
        xbp[c4] = make_float4(xv[4 * c4], xv[4 * c4 + 1], xv[4 * c4 + 2], xv[4 * c4 + 3]);
    // gate projection on raw x (commutes with bicubic upsample)
    float4* gp = (float4*)(glo + (size_t)idx * 64);
#pragma unroll
    for (int e4 = 0; e4 < 16; e4++) {
        float r[4];
#pragma unroll
        for (int u = 0; u < 4; u++) {
            int e = e4 * 4 + u;
            float s = gb[e];
#pragma unroll
            for (int c = 0; c < 64; c++) s = fmaf(xv[c], gw[e * 64 + c], s);
            r[u] = s;
        }
        gp[e4] = make_float4(r[0], r[1], r[2], r[3]);
    }
    // pc1a x-part projection (bias + y-part added at hi-res)
    float4* pp = (float4*)(plo + (size_t)idx * 16);
#pragma unroll
    for (int e4 = 0; e4 < 4; e4++) {
        float r[4];
#pragma unroll
        for (int u = 0; u < 4; u++) {
            int e = e4 * 4 + u;
            float s = 0.f;
#pragma unroll
            for (int c = 0; c < 64; c++) s = fmaf(xv[c], pw[e * 67 + 3 + c], s);
            r[u] = s;
        }
        pp[e4] = make_float4(r[0], r[1], r[2], r[3]);
    }
    // layernorm + k projection
    float m = 0.f;
#pragma unroll
    for (int c = 0; c < 64; c++) m += xv[c];
    m *= (1.f / 64.f);
    float var = 0.f;
#pragma unroll
    for (int c = 0; c < 64; c++) {
        float d = xv[c] - m;
        var = fmaf(d, d, var);
    }
    var *= (1.f / 64.f);
    float rstd = rsqrtf(var + 1e-5f);
#pragma unroll
    for (int c = 0; c < 64; c++) xv[c] = (xv[c] - m) * rstd * lg[c] + lb[c];
    float4* kp = (float4*)(kb + (size_t)idx * 64);
#pragma unroll
    for (int e4 = 0; e4 < 16; e4++) {
        float r[4];
#pragma unroll
        for (int u = 0; u < 4; u++) {
            int e = e4 * 4 + u;
            float s = kbias[e];
#pragma unroll
            for (int c = 0; c < 64; c++) s = fmaf(xv[c], kw[e * 64 + c], s);
            r[u] = s;
        }
        kp[e4] = make_float4(r[0], r[1], r[2], r[3]);
    }
}

// ---------------- separable bicubic upsample of [g_lo(64)|p_lo(16)] -> gate bf16 chlast + f0 chlast ----------------
__global__ __launch_bounds__(256) void k_gp(const float* __restrict__ glo, const float* __restrict__ plo,
                                            const float* __restrict__ y,
                                            const float* __restrict__ paw, const float* __restrict__ pab,
                                            __hip_bfloat16* __restrict__ gate, float* __restrict__ f0) {
    __shared__ float v[68 * 81];  // [col][ch], stride 81 to spread banks
    int bid = blockIdx.x;
    int b = bid >> 10, i = (bid >> 1) & 511, j0 = (bid & 1) << 8;
    int t = threadIdx.x;
    int iy[4];
    float wy[4];
    bicubic_axis(i, 128, iy, wy);
    int c0 = (j0 >> 2) - 2;
    // vertical pass into LDS
    for (int e = t; e < 68 * 80; e += 256) {
        int ch = e % 80, lc = e / 80;
        int gc = c0 + lc;
        float val = 0.f;
        if ((unsigned)gc < 128u) {
            if (ch < 64) {
                val = wy[0] * glo[(size_t)((b * 128 + iy[0]) * 128 + gc) * 64 + ch] +
                      wy[1] * glo[(size_t)((b * 128 + iy[1]) * 128 + gc) * 64 + ch] +
                      wy[2] * glo[(size_t)((b * 128 + iy[2]) * 128 + gc) * 64 + ch] +
                      wy[3] * glo[(size_t)((b * 128 + iy[3]) * 128 + gc) * 64 + ch];
            } else {
                int cc = ch - 64;
                val = wy[0] * plo[(size_t)((b * 128 + iy[0]) * 128 + gc) * 16 + cc] +
                      wy[1] * plo[(size_t)((b * 128 + iy[1]) * 128 + gc) * 16 + cc] +
                      wy[2] * plo[(size_t)((b * 128 + iy[2]) * 128 + gc) * 16 + cc] +
                      wy[3] * plo[(size_t)((b * 128 + iy[3]) * 128 + gc) * 16 + cc];
            }
        }
        v[lc * 81 + ch] = val;
    }
    __syncthreads();
    // horizontal pass: one px per thread
    int j = j0 + t;
    int jx[4];
    float wx[4];
    bicubic_axis(j, 128, jx, wx);
    int lx0 = jx[0] - c0, lx1 = jx[1] - c0, lx2 = jx[2] - c0, lx3 = jx[3] - c0;
    float out[80];
#pragma unroll
    for (int ch = 0; ch < 80; ch++)
        out[ch] = wx[0] * v[lx0 * 81 + ch] + wx[1] * v[lx1 * 81 + ch] +
                  wx[2] * v[lx2 * 81 + ch] + wx[3] * v[lx3 * 81 + ch];
    size_t pxoff = ((size_t)b << 18) + ((size_t)i << 9) + j;
    // gate: sigmoid -> bf16 packed stores (ALL 64 channels)
    unsigned int uu[32];
#pragma unroll
    for (int k = 0; k < 32; k++) {
        unsigned short h0 = f2bf(sigm(out[2 * k]));
        unsigned short h1 = f2bf(sigm(out[2 * k + 1]));
        uu[k] = (unsigned int)h0 | ((unsigned int)h1 << 16);
    }
    uint4* gp4 = (uint4*)((unsigned short*)gate + pxoff * 64);
#pragma unroll
    for (int k4 = 0; k4 < 8; k4++)
        gp4[k4] = make_uint4(uu[4 * k4], uu[4 * k4 + 1], uu[4 * k4 + 2], uu[4 * k4 + 3]);
    // f0 = up(p_lo) + W_y*y + b
    float yc0 = y[((size_t)(b * 3 + 0) << 18) + ((size_t)i << 9) + j];
    float yc1 = y[((size_t)(b * 3 + 1) << 18) + ((size_t)i << 9) + j];
    float yc2 = y[((size_t)(b * 3 + 2) << 18) + ((size_t)i << 9) + j];
    float4* fp = (float4*)(f0 + pxoff * 16);
#pragma unroll
    for (int e4 = 0; e4 < 4; e4++) {
        float r[4];
#pragma unroll
        for (int u = 0; u < 4; u++) {
            int oc = e4 * 4 + u;
            r[u] = out[64 + oc] + pab[oc] + yc0 * paw[oc * 67 + 0] + yc1 * paw[oc * 67 + 1] + yc2 * paw[oc * 67 + 2];
        }
        fp[e4] = make_float4(r[0], r[1], r[2], r[3]);
    }
}

// ---------------- 5x5 conv 16->16 pad2, LDS-staged tile (8x32, 34.6KB -> 4 blk/CU) ----------------
__global__ __launch_bounds__(256) void k_conv5(const float* __restrict__ fin,
                                               const float* __restrict__ wT,
                                               const float* __restrict__ bias,
                                               float* __restrict__ fout) {
    __shared__ float lds[12 * 36 * 20];  // 34,560 B
    int tid = threadIdx.x;
    int bid = blockIdx.x;  // 2048 = 2 * 64 * 16
    int seg = bid & 15, it = (bid >> 4) & 63, b = bid >> 10;
    int i0 = it * 8, j0 = seg * 32;
    for (int s = tid; s < 1728; s += 256) {  // 12*36 px * 4 parts
        int part = s & 3, px = s >> 2;
        int row = px / 36, col = px - row * 36;
        int gi = i0 - 2 + row, gj = j0 - 2 + col;
        float4 v = make_float4(0.f, 0.f, 0.f, 0.f);
        if ((unsigned)gi < 512u && (unsigned)gj < 512u)
            v = *(const float4*)(fin + (((size_t)b << 18) + ((size_t)gi << 9) + gj) * 16 + part * 4);
        *(float4*)(&lds[(row * 36 + col) * 20 + part * 4]) = v;
    }
    __syncthreads();
    int tx = tid & 31, ty = tid >> 5;
    float acc[16];
#pragma unroll
    for (int oc = 0; oc < 16; oc++) acc[oc] = bias[oc];
#pragma unroll
    for (int ky = 0; ky < 5; ky++) {
#pragma unroll
        for (int kx = 0; kx < 5; kx++) {
            const float* p = &lds[((ty + ky) * 36 + tx + kx) * 20];
            float vv[16];
            *(float4*)(vv + 0) = *(const float4*)(p + 0);
            *(float4*)(vv + 4) = *(const float4*)(p + 4);
            *(float4*)(vv + 8) = *(const float4*)(p + 8);
            *(float4*)(vv + 12) = *(const float4*)(p + 12);
            const float* wp = wT + (ky * 5 + kx) * 256;
#pragma unroll
            for (int ic = 0; ic < 16; ic++) {
                float v = vv[ic];
#pragma unroll
                for (int oc = 0; oc < 16; oc++)
                    acc[oc] = fmaf(v, wp[ic * 16 + oc], acc[oc]);
            }
        }
    }
    int i = i0 + ty, j = j0 + tx;
    float4* op = (float4*)(fout + (((size_t)b << 18) + ((size_t)i << 9) + j) * 16);
    op[0] = make_float4(acc[0], acc[1], acc[2], acc[3]);
    op[1] = make_float4(acc[4], acc[5], acc[6], acc[7]);
    op[2] = make_float4(acc[8], acc[9], acc[10], acc[11]);
    op[3] = make_float4(acc[12], acc[13], acc[14], acc[15]);
}

// ---------------- 3x3 conv 16->16 pad1 + relu, LDS-staged ----------------
__global__ __launch_bounds__(256) void k_conv3r(const float* __restrict__ fin,
                                                const float* __restrict__ wT,
                                                const float* __restrict__ bias,
                                                float* __restrict__ fout) {
    __shared__ float lds[6 * 66 * 20];  // 31,680 B
    int tid = threadIdx.x;
    int bid = blockIdx.x;
    int seg = bid & 7, it = (bid >> 3) & 127, b = bid >> 10;
    int i0 = it * 4, j0 = seg * 64;
    for (int s = tid; s < 1584; s += 256) {  // 6*66 px * 4 parts
        int part = s & 3, px = s >> 2;
        int row = px / 66, col = px - row * 66;
        int gi = i0 - 1 + row, gj = j0 - 1 + col;
        float4 v = make_float4(0.f, 0.f, 0.f, 0.f);
        if ((unsigned)gi < 512u && (unsigned)gj < 512u)
            v = *(const float4*)(fin + (((size_t)b << 18) + ((size_t)gi << 9) + gj) * 16 + part * 4);
        *(float4*)(&lds[(row * 66 + col) * 20 + part * 4]) = v;
    }
    __syncthreads();
    int tx = tid & 63, ty = tid >> 6;
    float acc[16];
#pragma unroll
    for (int oc = 0; oc < 16; oc++) acc[oc] = bias[oc];
#pragma unroll
    for (int ky = 0; ky < 3; ky++) {
#pragma unroll
        for (int kx = 0; kx < 3; kx++) {
            const float* p = &lds[((ty + ky) * 66 + tx + kx) * 20];
            float vv[16];
            *(float4*)(vv + 0) = *(const float4*)(p + 0);
            *(float4*)(vv + 4) = *(const float4*)(p + 4);
            *(float4*)(vv + 8) = *(const float4*)(p + 8);
            *(float4*)(vv + 12) = *(const float4*)(p + 12);
            const float* wp = wT + (ky * 3 + kx) * 256;
#pragma unroll
            for (int ic = 0; ic < 16; ic++) {
                float v = vv[ic];
#pragma unroll
                for (int oc = 0; oc < 16; oc++)
                    acc[oc] = fmaf(v, wp[ic * 16 + oc], acc[oc]);
            }
        }
    }
    int i = i0 + ty, j = j0 + tx;
    float4* op = (float4*)(fout + (((size_t)b << 18) + ((size_t)i << 9) + j) * 16);
    op[0] = make_float4(fmaxf(acc[0], 0.f), fmaxf(acc[1], 0.f), fmaxf(acc[2], 0.f), fmaxf(acc[3], 0.f));
    op[1] = make_float4(fmaxf(acc[4], 0.f), fmaxf(acc[5], 0.f), fmaxf(acc[6], 0.f), fmaxf(acc[7], 0.f));
    op[2] = make_float4(fmaxf(acc[8], 0.f), fmaxf(acc[9], 0.f), fmaxf(acc[10], 0.f), fmaxf(acc[11], 0.f));
    op[3] = make_float4(fmaxf(acc[12], 0.f), fmaxf(acc[13], 0.f), fmaxf(acc[14], 0.f), fmaxf(acc[15], 0.f));
}

// ---------------- spa2(t)+f1 residual, frq chain, cat -> f8 (LDS-staged 3x3) ----------------
__global__ __launch_bounds__(256) void k_tail(const float* __restrict__ f1,
                                              const float* __restrict__ t,
                                              const float* __restrict__ wT2,
                                              const float* __restrict__ s2b,
                                              const float* __restrict__ q1w, const float* __restrict__ q1b,
                                              const float* __restrict__ q2w, const float* __restrict__ q2b,
                                              const float* __restrict__ cw_, const float* __restrict__ cb_,
                                              float* __restrict__ f8) {
    __shared__ float lds[6 * 66 * 20];
    int tid = threadIdx.x;
    int bid = blockIdx.x;
    int seg = bid & 7, it = (bid >> 3) & 127, b = bid >> 10;
    int i0 = it * 4, j0 = seg * 64;
    for (int s = tid; s < 1584; s += 256) {
        int part = s & 3, px = s >> 2;
        int row = px / 66, col = px - row * 66;
        int gi = i0 - 1 + row, gj = j0 - 1 + col;
        float4 v = make_float4(0.f, 0.f, 0.f, 0.f);
        if ((unsigned)gi < 512u && (unsigned)gj < 512u)
            v = *(const float4*)(t + (((size_t)b << 18) + ((size_t)gi << 9) + gj) * 16 + part * 4);
        *(float4*)(&lds[(row * 66 + col) * 20 + part * 4]) = v;
    }
    __syncthreads();
    int tx = tid & 63, ty = tid >> 6;
    int i = i0 + ty, j = j0 + tx;
    float sp[16];
#pragma unroll
    for (int oc = 0; oc < 16; oc++) sp[oc] = s2b[oc];
#pragma unroll
    for (int ky = 0; ky < 3; ky++) {
#pragma unroll
        for (int kx = 0; kx < 3; kx++) {
            const float* p = &lds[((ty + ky) * 66 + tx + kx) * 20];
            float vv[16];
            *(float4*)(vv + 0) = *(const float4*)(p + 0);
            *(float4*)(vv + 4) = *(const float4*)(p + 4);
            *(float4*)(vv + 8) = *(const float4*)(p + 8);
            *(float4*)(vv + 12) = *(const float4*)(p + 12);
            const float* wp = wT2 + (ky * 3 + kx) * 256;
#pragma unroll
            for (int ic = 0; ic < 16; ic++) {
                float v = vv[ic];
#pragma unroll
                for (int oc = 0; oc < 16; oc++)
                    sp[oc] = fmaf(v, wp[ic * 16 + oc], sp[oc]);
            }
        }
    }
    // own-pixel f1 (residual + frq input)
    float fv[16];
    const float4* f1p = (const float4*)(f1 + (((size_t)b << 18) + ((size_t)i << 9) + j) * 16);
    *(float4*)(fv + 0) = f1p[0];
    *(float4*)(fv + 4) = f1p[1];
    *(float4*)(fv + 8) = f1p[2];
    *(float4*)(fv + 12) = f1p[3];
#pragma unroll
    for (int c = 0; c < 16; c++) sp[c] += fv[c];
    float mid[16];
#pragma unroll
    for (int r = 0; r < 16; r++) {
        float m = q1b[r];
#pragma unroll
        for (int c = 0; c < 16; c++) m = fmaf(fv[c], q1w[r * 16 + c], m);
        mid[r] = fmaxf(m, 0.f);
    }
    float fo[16];
#pragma unroll
    for (int r = 0; r < 16; r++) {
        float m = q2b[r];
#pragma unroll
        for (int c = 0; c < 16; c++) m = fmaf(mid[c], q2w[r * 16 + c], m);
        fo[r] = m;
    }
    float r8[8];
#pragma unroll
    for (int o = 0; o < 8; o++) {
        float a = cb_[o];
#pragma unroll
        for (int c = 0; c < 16; c++) a = fmaf(sp[c], cw_[o * 32 + c], a);
#pragma unroll
        for (int c = 0; c < 16; c++) a = fmaf(fo[c], cw_[o * 32 + 16 + c], a);
        r8[o] = a;
    }
    float4* op = (float4*)(f8 + (((size_t)b << 18) + ((size_t)i << 9) + j) * 8);
    op[0] = make_float4(r8[0], r8[1], r8[2], r8[3]);
    op[1] = make_float4(r8[4], r8[5], r8[6], r8[7]);
}

// ---------------- pooled mean partials (channel-last f8) ----------------
__global__ __launch_bounds__(256) void k_pool(const float* __restrict__ f8, float* __restrict__ partials) {
    int b = blockIdx.x >> 4, blk = blockIdx.x & 15;
    const float4* fp = (const float4*)(f8 + (((size_t)b) << 18) * 8);
    float acc[8];
#pragma unroll
    for (int c = 0; c < 8; c++) acc[c] = 0.f;
    int p0 = blk * 16384;
    for (int p = p0 + threadIdx.x; p < p0 + 16384; p += 256) {
        float4 a0 = fp[p * 2], a1 = fp[p * 2 + 1];
        acc[0] += a0.x; acc[1] += a0.y; acc[2] += a0.z; acc[3] += a0.w;
        acc[4] += a1.x; acc[5] += a1.y; acc[6] += a1.z; acc[7] += a1.w;
    }
#pragma unroll
    for (int off = 32; off; off >>= 1) {
#pragma unroll
        for (int c = 0; c < 8; c++) acc[c] += __shfl_down(acc[c], off, 64);
    }
    __shared__ float ls[4][8];
    int lane = threadIdx.x & 63, wv = threadIdx.x >> 6;
    if (lane == 0) {
#pragma unroll
        for (int c = 0; c < 8; c++) ls[wv][c] = acc[c];
    }
    __syncthreads();
    if (threadIdx.x < 8) {
        float s = ls[0][threadIdx.x] + ls[1][threadIdx.x] + ls[2][threadIdx.x] + ls[3][threadIdx.x];
        partials[(b * 8 + threadIdx.x) * 16 + blk] = s;
    }
}

__global__ void k_se(const float* __restrict__ partials,
                     const float* __restrict__ w1, const float* __restrict__ b1,
                     const float* __restrict__ w2, const float* __restrict__ b2,
                     float* __restrict__ cw) {
    int b = threadIdx.x;
    if (b >= 2) return;
    float pooled[8];
#pragma unroll
    for (int c = 0; c < 8; c++) {
        float s = 0.f;
#pragma unroll
        for (int k = 0; k < 16; k++) s += partials[(b * 8 + c) * 16 + k];
        pooled[c] = s * (1.f / 262144.f);
    }
    float mid[2];
#pragma unroll
    for (int r = 0; r < 2; r++) {
        float m = b1[r];
#pragma unroll
        for (int c = 0; c < 8; c++) m = fmaf(w1[r * 8 + c], pooled[c], m);
        mid[r] = fmaxf(m, 0.f);
    }
#pragma unroll
    for (int c = 0; c < 8; c++) {
        float v = b2[c] + w2[c * 2 + 0] * mid[0] + w2[c * 2 + 1] * mid[1];
        cw[b * 8 + c] = 1.f / (1.f + __expf(-v));
    }
}

// ---------------- enc = conv1x1_8->64(f8*cw) + fused LN(lny) + q-proj -> qbuf bf16 chlast ----------------
__global__ __launch_bounds__(256) void k_pc3(const float* __restrict__ f8, const float* __restrict__ cw,
                                             const float* __restrict__ w, const float* __restrict__ bias,
                                             const float* __restrict__ lg, const float* __restrict__ lb,
                                             const float* __restrict__ qw, const float* __restrict__ qbias,
                                             float* __restrict__ enc, unsigned short* __restrict__ qbuf) {
    int idx = blockIdx.x * 256 + threadIdx.x;
    int b = idx >> 18;
    size_t hi = (size_t)idx & 262143;
    const float4* fp = (const float4*)(f8 + (size_t)idx * 8);
    float4 a0 = fp[0], a1 = fp[1];
    float v[8] = {a0.x, a0.y, a0.z, a0.w, a1.x, a1.y, a1.z, a1.w};
#pragma unroll
    for (int c = 0; c < 8; c++) v[c] *= cw[b * 8 + c];
    float yn[64];
#pragma unroll
    for (int oc = 0; oc < 64; oc++) {
        float a = bias[oc];
#pragma unroll
        for (int c = 0; c < 8; c++) a = fmaf(v[c], w[oc * 8 + c], a);
        yn[oc] = a;
        enc[((size_t)(b * 64 + oc) << 18) + hi] = a;
    }
    // layernorm (lny) over the 64 channels (all in regs)
    float m = 0.f;
#pragma unroll
    for (int c = 0; c < 64; c++) m += yn[c];
    m *= (1.f / 64.f);
    float var = 0.f;
#pragma unroll
    for (int c = 0; c < 64; c++) {
        float d = yn[c] - m;
        var = fmaf(d, d, var);
    }
    var *= (1.f / 64.f);
    float rstd = rsqrtf(var + 1e-5f);
#pragma unroll
    for (int c = 0; c < 64; c++) yn[c] = (yn[c] - m) * rstd * lg[c] + lb[c];
    // q projection (wave-uniform weight reads -> s_load), store bf16 channel-last
    unsigned short* qp = qbuf + (size_t)idx * 64;
    for (int e0 = 0; e0 < 64; e0 += 8) {
        float qv[8];
#pragma unroll
        for (int u = 0; u < 8; u++) {
            float s = qbias[e0 + u];
#pragma unroll
            for (int c = 0; c < 64; c++) s = fmaf(yn[c], qw[(e0 + u) * 64 + c], s);
            qv[u] = s;
        }
        unsigned int pk[4];
#pragma unroll
        for (int u = 0; u < 4; u++)
            pk[u] = (unsigned int)f2bf(qv[2 * u]) | ((unsigned int)f2bf(qv[2 * u + 1]) << 16);
        *(uint4*)(qp + e0) = make_uint4(pk[0], pk[1], pk[2], pk[3]);
    }
}

// ---------------- attention + blend: row-tile (1 i x 64 j), 4 threads/pixel ----------------
// Wave lanes for a fixed channel cover 16 consecutive j -> all planar accesses are full
// 64B segments. K and X halos (5x20 low-res pts) time-share one LDS buffer.
__global__ __launch_bounds__(256, 4) void k_attn(const float* __restrict__ enc,
                                                 const __hip_bfloat16* __restrict__ gate,
                                                 const unsigned short* __restrict__ qb,
                                                 const float* __restrict__ kb, const float* __restrict__ xbv,
                                                 float* __restrict__ sapa, float* __restrict__ fin) {
    __shared__ float tile[100 * 68];  // 27,200 B, stride 68 -> <=2-way bank overlap (free)
    int tid = threadIdx.x;
    int bid = blockIdx.x;  // 2 * 512 * 8
    int b = bid >> 12, i = (bid >> 3) & 511, jb = bid & 7;
    int j0 = jb << 6;
    int h = i >> 2;          // low-res row (fixed for the whole block)
    int wbase = j0 >> 2;     // first low-res col of the tile
    int cg = tid & 3, px = tid >> 2;
    int j = j0 + px;
    size_t pix = ((size_t)b << 18) + ((size_t)i << 9) + j;
    // this thread's 16 q-components (e-group = cg), bf16 channel-last (nontemporal: read-once)
    const u32x4* qp = (const u32x4*)(qb + pix * 64 + cg * 16);
    u32x4 q0 = __builtin_nontemporal_load(qp), q1 = __builtin_nontemporal_load(qp + 1);
    unsigned int qu[8] = {q0[0], q0[1], q0[2], q0[3], q1[0], q1[1], q1[2], q1[3]};
    float q[16];
#pragma unroll
    for (int k = 0; k < 8; k++) {
        q[2 * k] = bf2f((unsigned short)(qu[k] & 0xffff));
        q[2 * k + 1] = bf2f((unsigned short)(qu[k] >> 16));
    }
    // ---- phase 1: stage K halo (5 rows x 20 cols), zero-filled OOB ----
    for (int s = tid; s < 1600; s += 256) {
        int p = s >> 4, e4 = s & 15;
        int row = p / 20, col = p - row * 20;
        int hh = h - 2 + row, ww = wbase - 2 + col;
        float4 val = make_float4(0.f, 0.f, 0.f, 0.f);
        if ((unsigned)hh < 128u && (unsigned)ww < 128u)
            val = ((const float4*)(kb + (size_t)((b * 128 + hh) * 128 + ww) * 64))[e4];
        *(float4*)(tile + p * 68 + e4 * 4) = val;
    }
    __syncthreads();
    // ---- QK partial logits over my 16 e's ----
    int wl = px >> 2;  // 0..15 local low-res col
    float a[25];
#pragma unroll
    for (int dy = 0; dy < 5; dy++) {
#pragma unroll
        for (int dx = 0; dx < 5; dx++) {
            int lp = dy * 20 + wl + dx;
            const float4* kp = (const float4*)(tile + lp * 68 + cg * 16);
            float s = 0.f;
#pragma unroll
            for (int e4 = 0; e4 < 4; e4++) {
                float4 kv = kp[e4];
                s = fmaf(q[4 * e4 + 0], kv.x, s);
                s = fmaf(q[4 * e4 + 1], kv.y, s);
                s = fmaf(q[4 * e4 + 2], kv.z, s);
                s = fmaf(q[4 * e4 + 3], kv.w, s);
            }
            a[dy * 5 + dx] = s;
        }
    }
    // quad reduce (4 threads of one pixel are consecutive lanes)
#pragma unroll
    for (int p = 0; p < 25; p++) {
        a[p] += __shfl_xor(a[p], 1, 4);
        a[p] += __shfl_xor(a[p], 2, 4);
    }
    // softmax (replicated x4, cheap; OOB taps have exact 0 logit)
    float mx = a[0];
#pragma unroll
    for (int p = 1; p < 25; p++) mx = fmaxf(mx, a[p]);
    float Z = 0.f;
#pragma unroll
    for (int p = 0; p < 25; p++) {
        a[p] = __expf(a[p] - mx);
        Z += a[p];
    }
    float invZ = 1.f / Z;
    __syncthreads();  // all QK reads done before overwriting tile
    // ---- phase 2: stage X halo into the same buffer ----
    for (int s = tid; s < 1600; s += 256) {
        int p = s >> 4, e4 = s & 15;
        int row = p / 20, col = p - row * 20;
        int hh = h - 2 + row, ww = wbase - 2 + col;
        float4 val = make_float4(0.f, 0.f, 0.f, 0.f);
        if ((unsigned)hh < 128u && (unsigned)ww < 128u)
            val = ((const float4*)(xbv + (size_t)((b * 128 + hh) * 128 + ww) * 64))[e4];
        *(float4*)(tile + p * 68 + e4 * 4) = val;
    }
    __syncthreads();
    // ---- PV over my 16 channels ----
    float o[16];
#pragma unroll
    for (int k = 0; k < 16; k++) o[k] = 0.f;
#pragma unroll
    for (int dy = 0; dy < 5; dy++) {
#pragma unroll
        for (int dx = 0; dx < 5; dx++) {
            float wp = a[dy * 5 + dx];
            int lp = dy * 20 + wl + dx;
            const float4* xp = (const float4*)(tile + lp * 68 + cg * 16);
#pragma unroll
            for (int e4 = 0; e4 < 4; e4++) {
                float4 xv = xp[e4];
                o[4 * e4 + 0] = fmaf(wp, xv.x, o[4 * e4 + 0]);
                o[4 * e4 + 1] = fmaf(wp, xv.y, o[4 * e4 + 1]);
                o[4 * e4 + 2] = fmaf(wp, xv.z, o[4 * e4 + 2]);
                o[4 * e4 + 3] = fmaf(wp, xv.w, o[4 * e4 + 3]);
            }
        }
    }
    // ---- epilogue: gate (chlast bf16, nontemporal), enc read + sapa/fin nontemporal writes ----
    const u32x4* gp4 = (const u32x4*)((const unsigned short*)gate + pix * 64 + cg * 16);
    u32x4 g0 = __builtin_nontemporal_load(gp4), g1 = __builtin_nontemporal_load(gp4 + 1);
    unsigned int gu[8] = {g0[0], g0[1], g0[2], g0[3], g1[0], g1[1], g1[2], g1[3]};
    size_t obase = ((size_t)b << 24) + ((size_t)i << 9) + j;
    const float* ep = enc + obase;
#pragma unroll
    for (int cc = 0; cc < 16; cc++) {
        int c = cg * 16 + cc;
        size_t oidx = obase + ((size_t)c << 18);
        float sv = o[cc] * invZ;
        __builtin_nontemporal_store(sv, &sapa[oidx]);
        unsigned int wbits = gu[cc >> 1];
        unsigned short hb = (cc & 1) ? (unsigned short)(wbits >> 16) : (unsigned short)(wbits & 0xffff);
        float gv = bf2f(hb);
        float ev = ep[(size_t)c << 18];
        __builtin_nontemporal_store(gv * sv + (1.f - gv) * ev, &fin[oidx]);
    }
}

extern "C" void kernel_launch(void* const* d_in, const int* in_sizes, int n_in,
                              void* d_out, int out_size, void* d_ws, size_t ws_size,
                              hipStream_t stream) {
    const float* x = (const float*)d_in[0];
    const float* y = (const float*)d_in[1];
    const float* gate_w = (const float*)d_in[2];
    const float* gate_b = (const float*)d_in[3];
    const float* pc1a_w = (const float*)d_in[4];
    const float* pc1a_b = (const float*)d_in[5];
    const float* pc1b_w = (const float*)d_in[6];
    const float* pc1b_b = (const float*)d_in[7];
    const float* spa1_w = (const float*)d_in[8];
    const float* spa1_b = (const float*)d_in[9];
    const float* spa2_w = (const float*)d_in[10];
    const float* spa2_b = (const float*)d_in[11];
    const float* frq1_w = (const float*)d_in[12];
    const float* frq1_b = (const float*)d_in[13];
    const float* frq2_w = (const float*)d_in[14];
    const float* frq2_b = (const float*)d_in[15];
    const float* cat_w = (const float*)d_in[16];
    const float* cat_b = (const float*)d_in[17];
    const float* ca1_w = (const float*)d_in[18];
    const float* ca1_b = (const float*)d_in[19];
    const float* ca2_w = (const float*)d_in[20];
    const float* ca2_b = (const float*)d_in[21];
    const float* pc3_w = (const float*)d_in[22];
    const float* pc3_b = (const float*)d_in[23];
    const float* lny_g = (const float*)d_in[24];
    const float* lny_b = (const float*)d_in[25];
    const float* lnx_g = (const float*)d_in[26];
    const float* lnx_b = (const float*)d_in[27];
    const float* q_w = (const float*)d_in[28];
    const float* q_b = (const float*)d_in[29];
    const float* k_w = (const float*)d_in[30];
    const float* k_b = (const float*)d_in[31];

    float* out = (float*)d_out;
    float* finalp = out;
    float* sapap = out + 33554432;
    float* encp = out + 67108864;

    char* ws = (char*)d_ws;
    __hip_bfloat16* gate = (__hip_bfloat16*)ws;   // 67,108,864 B  [b][i][j][64] bf16
    float* f0 = (float*)(ws + 67108864);          // 33,554,432 B  [b][i][j][16]
    float* f1 = (float*)(ws + 100663296);         // 33,554,432 B  [b][i][j][16]
    float* f8 = (float*)(ws + 134217728);         // 16,777,216 B  [b][i][j][8]
    float* kbuf = (float*)(ws + 150994944);       // 8,388,608 B   [b][h][w][64]
    float* xbuf = (float*)(ws + 159383552);       // 8,388,608 B   [b][h][w][64]
    float* partials = (float*)(ws + 167772160);   // 1,024 B
    float* cw = (float*)(ws + 167773184);         // 64 B
    float* wT5 = (float*)(ws + 167773248);        // 25,600 B [25][16][16]
    float* wT3a = (float*)(ws + 167798848);       // 9,216 B  [9][16][16]
    float* wT3b = (float*)(ws + 167808064);       // 9,216 B  [9][16][16]
    // aliases: g_lo/p_lo live in f1 region (consumed by k_gp before conv5 writes f1)
    float* glo = f1;                               // 8,388,608 B [b][h][w][64]
    float* plo = f1 + 2097152;                     // 2,097,152 B [b][h][w][16]
    float* tbuf = f0;                              // reuse f0 after conv5 consumed it
    // qbuf aliases f0+f1 (both dead after k_tail; k_pc3 writes it, k_attn reads it)
    unsigned short* qbuf = (unsigned short*)(ws + 67108864);  // 67,108,864 B [b][i][j][64] bf16

    dim3 blk(256);
    dim3 gridHi(2048);
    dim3 gridConv(2048);  // conv5: 2 x 64 i-tiles x 16 col-segs; conv3/tail: 2 x 128 x 8

    k_prep<<<dim3(25), blk, 0, stream>>>(pc1b_w, spa1_w, spa2_w, wT5, wT3a, wT3b);
    k_low<<<dim3(128), blk, 0, stream>>>(x, gate_w, gate_b, pc1a_w, lnx_g, lnx_b, k_w, k_b,
                                         kbuf, xbuf, glo, plo);
    k_gp<<<gridHi, blk, 0, stream>>>(glo, plo, y, pc1a_w, pc1a_b, gate, f0);
    k_conv5<<<gridConv, blk, 0, stream>>>(f0, wT5, pc1b_b, f1);
    k_conv3r<<<gridConv, blk, 0, stream>>>(f1, wT3a, spa1_b, tbuf);
    k_tail<<<gridConv, blk, 0, stream>>>(f1, tbuf, wT3b, spa2_b, frq1_w, frq1_b,
                                         frq2_w, frq2_b, cat_w, cat_b, f8);
    k_pool<<<dim3(32), blk, 0, stream>>>(f8, partials);
    k_se<<<dim3(1), dim3(64), 0, stream>>>(partials, ca1_w, ca1_b, ca2_w, ca2_b, cw);
    k_pc3<<<gridHi, blk, 0, stream>>>(f8, cw, pc3_w, pc3_b, lny_g, lny_b, q_w, q_b, encp, qbuf);
    k_attn<<<dim3(8192), blk, 0, stream>>>(encp, gate, qbuf, kbuf, xbuf, sapap, finalp);
}